// Round 2
// baseline (5368.774 us; speedup 1.0000x reference)
//
#include <hip/hip_runtime.h>
#include <cstdint>

// ---------------------------------------------------------------------------
// Problem constants: B=8, S=512, H=1024, NH=8, DH=128, INTER=3072, SPAN=512,
// LSTM_H=512. Output fp32 [B,S,H] = concat(hf, hr).
// ---------------------------------------------------------------------------

typedef __bf16 bf8_t __attribute__((ext_vector_type(8)));
typedef float f32x4 __attribute__((ext_vector_type(4)));

__device__ __forceinline__ unsigned short f2bf(float f) {
  union { float f; unsigned int u; } v; v.f = f;
  unsigned int r = v.u + 0x7fffu + ((v.u >> 16) & 1u);
  return (unsigned short)(r >> 16);
}
__device__ __forceinline__ float bf2f(unsigned short s) {
  union { unsigned int u; float f; } v; v.u = ((unsigned int)s) << 16;
  return v.f;
}
__device__ __forceinline__ float bflo(unsigned int u) {
  union { unsigned int u; float f; } v; v.u = u << 16; return v.f;
}
__device__ __forceinline__ float bfhi(unsigned int u) {
  union { unsigned int u; float f; } v; v.u = u & 0xffff0000u; return v.f;
}

// async global->LDS, 16B per lane; lds dest is wave-uniform base + lane*16
__device__ __forceinline__ void async16(const void* g, void* l) {
  __builtin_amdgcn_global_load_lds(
      (const __attribute__((address_space(1))) void*)g,
      (__attribute__((address_space(3))) void*)l, 16, 0, 0);
}

// sentinel: ws_size too small -> make absmax unmistakably huge
__global__ void k_sentinel(float* out) { out[0] = 1e30f; }

// ---------------------------------------------------------------------------
// fp32 -> bf16 cast (n divisible by 1024)
// ---------------------------------------------------------------------------
__global__ void k_cast_bf16(const float* __restrict__ in, unsigned short* __restrict__ out) {
  long i = ((long)blockIdx.x * 256 + threadIdx.x) * 4;
  float4 v = *(const float4*)(in + i);
  unsigned int a = (unsigned int)f2bf(v.x) | ((unsigned int)f2bf(v.y) << 16);
  unsigned int b = (unsigned int)f2bf(v.z) | ((unsigned int)f2bf(v.w) << 16);
  *(uint2*)(out + i) = make_uint2(a, b);
}

// build qkv bias [3072] = (q_bias, 0, v_bias) and bsum = bih+bhh per dir
__global__ void k_build_bias(const float* qb, const float* vb, float* qkvBias,
                             const float* bihf, const float* bhhf, float* bsf,
                             const float* bihr, const float* bhhr, float* bsr) {
  int i = blockIdx.x * 256 + threadIdx.x;
  if (i < 3072) {
    float v;
    if (i < 1024) v = qb[i];
    else if (i < 2048) v = 0.f;
    else v = vb[i - 2048];
    qkvBias[i] = v;
  }
  if (i < 2048) {
    bsf[i] = bihf[i] + bhhf[i];
    bsr[i] = bihr[i] + bhhr[i];
  }
}

// ---------------------------------------------------------------------------
// LayerNorm over 1024 cols. in (+res) -> outF (fp32, optional) + outB (bf16,
// optional). res row index = row & resMask (mask=511 for pos_emb broadcast).
// ---------------------------------------------------------------------------
__global__ __launch_bounds__(256) void k_layernorm(
    const float* __restrict__ in, const float* __restrict__ res, unsigned int resMask,
    const float* __restrict__ gamma, const float* __restrict__ beta,
    float* __restrict__ outF, unsigned short* __restrict__ outB) {
  const int row = blockIdx.x;
  const int tid = threadIdx.x;
  float4 v = ((const float4*)(in + (long)row * 1024))[tid];
  if (res) {
    float4 r = ((const float4*)(res + (long)(row & resMask) * 1024))[tid];
    v.x += r.x; v.y += r.y; v.z += r.z; v.w += r.w;
  }
  float s = v.x + v.y + v.z + v.w;
  float q = v.x * v.x + v.y * v.y + v.z * v.z + v.w * v.w;
#pragma unroll
  for (int o = 32; o; o >>= 1) { s += __shfl_down(s, o); q += __shfl_down(q, o); }
  __shared__ float rs[4], rq[4];
  const int wave = tid >> 6, lane = tid & 63;
  if (lane == 0) { rs[wave] = s; rq[wave] = q; }
  __syncthreads();
  s = rs[0] + rs[1] + rs[2] + rs[3];
  q = rq[0] + rq[1] + rq[2] + rq[3];
  const float mean = s * (1.f / 1024.f);
  const float var = q * (1.f / 1024.f) - mean * mean;
  const float rstd = rsqrtf(var + 1e-7f);
  float4 g4 = ((const float4*)gamma)[tid];
  float4 b4 = ((const float4*)beta)[tid];
  float4 o4;
  o4.x = (v.x - mean) * rstd * g4.x + b4.x;
  o4.y = (v.y - mean) * rstd * g4.y + b4.y;
  o4.z = (v.z - mean) * rstd * g4.z + b4.z;
  o4.w = (v.w - mean) * rstd * g4.w + b4.w;
  if (outF) ((float4*)(outF + (long)row * 1024))[tid] = o4;
  if (outB) {
    unsigned int a = (unsigned int)f2bf(o4.x) | ((unsigned int)f2bf(o4.y) << 16);
    unsigned int b = (unsigned int)f2bf(o4.z) | ((unsigned int)f2bf(o4.w) << 16);
    ((uint2*)(outB + (long)row * 1024))[tid] = make_uint2(a, b);
  }
}

// ---------------------------------------------------------------------------
// bf16 MFMA GEMM: C[M,N] = A[M,K] @ B[N,K]^T, 128x128 tile, BK=32,
// global_load_lds staging (m93/m97 structure). Epilogue:
//   v = (acc + bias[col]) * scale;  MODE 0: fp32 store, 1: bf16, 2: gelu->bf16
// All of M,N multiples of 128; K multiple of 32.
// ---------------------------------------------------------------------------
template <int MODE>
__global__ __launch_bounds__(256) void k_gemm_bt(
    const unsigned short* __restrict__ A, int lda,
    const unsigned short* __restrict__ Bm, int ldb,
    void* __restrict__ Cv, int ldc,
    int K, const float* __restrict__ bias, float scale) {
  __shared__ __align__(16) unsigned short As[128 * 32];
  __shared__ __align__(16) unsigned short Bs[128 * 32];
  const int tid = threadIdx.x;
  const int lane = tid & 63;
  const int wave = tid >> 6;
  const int n0 = blockIdx.x * 128;
  const int m0 = blockIdx.y * 128;
  const int srow = tid >> 2;          // 0..63
  const int scol = (tid & 3) * 8;     // 0,8,16,24
  const unsigned short* ag0 = A + (long)(m0 + srow) * lda + scol;
  const unsigned short* ag1 = A + (long)(m0 + 64 + srow) * lda + scol;
  const unsigned short* bg0 = Bm + (long)(n0 + srow) * ldb + scol;
  const unsigned short* bg1 = Bm + (long)(n0 + 64 + srow) * ldb + scol;
  unsigned short* asd0 = &As[(wave * 16) * 32];        // wave-uniform LDS dest
  unsigned short* asd1 = &As[(64 + wave * 16) * 32];
  unsigned short* bsd0 = &Bs[(wave * 16) * 32];
  unsigned short* bsd1 = &Bs[(64 + wave * 16) * 32];
  const int wm = wave >> 1, wn = wave & 1;
  const int mrow = lane & 15;
  const int kq = (lane >> 4) * 8;
  const f32x4 vzero = {0.f, 0.f, 0.f, 0.f};
  f32x4 acc[4][4];
#pragma unroll
  for (int i = 0; i < 4; ++i)
#pragma unroll
    for (int j = 0; j < 4; ++j) acc[i][j] = vzero;

  const int nk = K >> 5;
  for (int kt = 0; kt < nk; ++kt) {
    if (kt) __syncthreads();        // previous tile consumed
    async16(ag0, asd0); async16(ag1, asd1);
    async16(bg0, bsd0); async16(bg1, bsd1);
    ag0 += 32; ag1 += 32; bg0 += 32; bg1 += 32;
    __syncthreads();                // drains vmcnt -> staged data visible
    bf8_t af[4], bf[4];
#pragma unroll
    for (int i = 0; i < 4; ++i)
      af[i] = *(const bf8_t*)&As[(wm * 64 + i * 16 + mrow) * 32 + kq];
#pragma unroll
    for (int j = 0; j < 4; ++j)
      bf[j] = *(const bf8_t*)&Bs[(wn * 64 + j * 16 + mrow) * 32 + kq];
#pragma unroll
    for (int i = 0; i < 4; ++i)
#pragma unroll
      for (int j = 0; j < 4; ++j)
        acc[i][j] = __builtin_amdgcn_mfma_f32_16x16x32_bf16(af[i], bf[j], acc[i][j], 0, 0, 0);
  }
  const int quad = lane >> 4;
  const int cn = lane & 15;
  float* Cf = (float*)Cv;
  unsigned short* Cb = (unsigned short*)Cv;
#pragma unroll
  for (int i = 0; i < 4; ++i) {
#pragma unroll
    for (int j = 0; j < 4; ++j) {
#pragma unroll
      for (int r = 0; r < 4; ++r) {
        int row = m0 + wm * 64 + i * 16 + quad * 4 + r;
        int col = n0 + wn * 64 + j * 16 + cn;
        float v = acc[i][j][r];
        if (bias) v += bias[col];
        v *= scale;
        if (MODE == 2) v = 0.5f * v * (1.0f + erff(v * 0.70710678118654752f));
        long idx = (long)row * ldc + col;
        if (MODE == 0) Cf[idx] = v;
        else Cb[idx] = f2bf(v);
      }
    }
  }
}

// ---------------------------------------------------------------------------
// Attention core, one head per launch. Per (b, 16-row q-tile):
// scores = qk*scale + c2p + p2c; softmax; ctx = probs @ v.
//   c2p_h[b*512+q][rel], p2c_h[b*512+k][rel], rel = q-k+512 (clip is no-op).
// ---------------------------------------------------------------------------
__global__ __launch_bounds__(256) void k_attention(
    const unsigned short* __restrict__ qkv,
    const unsigned short* __restrict__ c2p,
    const unsigned short* __restrict__ p2c,
    unsigned short* __restrict__ ctx, int h) {
  const int tid = threadIdx.x;
  const int qt = blockIdx.x;   // 0..31
  const int b = blockIdx.y;    // 0..7
  const int q0 = qt * 16;
  __shared__ __align__(16) float sc[16][520];
  __shared__ __align__(16) float qs[16][128];

  // load q tile (biased, unscaled)
  for (int i = tid; i < 16 * 128; i += 256) {
    int ql = i >> 7, d = i & 127;
    qs[ql][d] = bf2f(qkv[((long)(b * 512 + q0 + ql)) * 3072 + h * 128 + d]);
  }
  __syncthreads();

  const float scale = 0.051031036307982884f;  // 1/sqrt(128*3)
  for (int pass = 0; pass < 2; ++pass) {
    const int k = tid + pass * 256;
    float4 kvf[32];
    const unsigned short* kp = qkv + ((long)(b * 512 + k)) * 3072 + 1024 + h * 128;
#pragma unroll
    for (int c = 0; c < 16; ++c) {
      uint4 u = ((const uint4*)kp)[c];
      kvf[2 * c + 0] = make_float4(bflo(u.x), bfhi(u.x), bflo(u.y), bfhi(u.y));
      kvf[2 * c + 1] = make_float4(bflo(u.z), bfhi(u.z), bflo(u.w), bfhi(u.w));
    }
    // p2c: row = b*512+k, col = (q0+ql)-k+512 -> contiguous in ql
    const unsigned short* pp = p2c + ((long)(b * 512 + k)) * 1024 + (q0 - k + 512);
    for (int ql = 0; ql < 16; ++ql) {
      float dot = 0.f;
#pragma unroll
      for (int dd = 0; dd < 32; ++dd) {
        float4 qf = ((const float4*)&qs[ql][0])[dd];
        dot += qf.x * kvf[dd].x + qf.y * kvf[dd].y + qf.z * kvf[dd].z + qf.w * kvf[dd].w;
      }
      sc[ql][k] = dot * scale + bf2f(pp[ql]);
    }
  }
  __syncthreads();

  // softmax rows (+ c2p add, contiguous per row: col = q - k + 512)
  const int wave = tid >> 6, lane = tid & 63;
#pragma unroll
  for (int rr = 0; rr < 4; ++rr) {
    const int r = wave * 4 + rr;
    const int q = q0 + r;
    const unsigned short* cp = c2p + ((long)(b * 512 + q)) * 1024 + (q + 512);
    float v[8];
#pragma unroll
    for (int i = 0; i < 8; ++i) {
      int k = lane + 64 * i;
      v[i] = sc[r][k] + bf2f(cp[-k]);
    }
    float m = v[0];
#pragma unroll
    for (int i = 1; i < 8; ++i) m = fmaxf(m, v[i]);
#pragma unroll
    for (int o = 32; o; o >>= 1) m = fmaxf(m, __shfl_xor(m, o));
    float ssum = 0.f;
#pragma unroll
    for (int i = 0; i < 8; ++i) { v[i] = __expf(v[i] - m); ssum += v[i]; }
#pragma unroll
    for (int o = 32; o; o >>= 1) ssum += __shfl_xor(ssum, o);
    const float inv = 1.0f / ssum;
#pragma unroll
    for (int i = 0; i < 8; ++i) sc[r][lane + 64 * i] = v[i] * inv;
  }
  __syncthreads();

  // ctx = probs @ v
  const int d = tid & 127;
  const int qg = tid >> 7;  // 0..1
  float acc[8] = {0, 0, 0, 0, 0, 0, 0, 0};
  const unsigned short* vp = qkv + ((long)(b * 512)) * 3072 + 2048 + h * 128 + d;
  for (int k = 0; k < 512; k += 4) {
    float v0 = bf2f(vp[(long)(k + 0) * 3072]);
    float v1 = bf2f(vp[(long)(k + 1) * 3072]);
    float v2 = bf2f(vp[(long)(k + 2) * 3072]);
    float v3 = bf2f(vp[(long)(k + 3) * 3072]);
#pragma unroll
    for (int qq = 0; qq < 8; ++qq) {
      float4 p = *(const float4*)&sc[qg * 8 + qq][k];
      acc[qq] += p.x * v0 + p.y * v1 + p.z * v2 + p.w * v3;
    }
  }
#pragma unroll
  for (int qq = 0; qq < 8; ++qq) {
    int q = q0 + qg * 8 + qq;
    ctx[((long)(b * 512 + q)) * 1024 + h * 128 + d] = f2bf(acc[qq]);
  }
}

// ---------------------------------------------------------------------------
// Bidirectional LSTM recurrence. Grid (32, 2): 32 blocks per direction, all
// co-resident (64 blocks << 256 CUs). Block owns 16 hidden channels
// (x 4 gates = 64 Whh rows) held persistently in registers as MFMA A
// fragments (wave g = gate g). Per step: flag-wait -> load h_prev (from
// d_out) into LDS B panel -> 16 chained MFMAs -> gate exchange in LDS ->
// elementwise c/h (c in regs of tid<128) -> write h to d_out -> release.
// Gate order i,f,g,o (torch). xW is bf16 [B][S][4*512].
// ---------------------------------------------------------------------------
__global__ __launch_bounds__(256) void k_lstm(
    const float* __restrict__ WhhF, const float* __restrict__ WhhR,
    const unsigned short* __restrict__ xWF, const unsigned short* __restrict__ xWR,
    float* __restrict__ out, int* __restrict__ flags) {
  const int tid = threadIdx.x;
  const int lane = tid & 63;
  const int g = tid >> 6;              // wave index = gate
  const int dir = blockIdx.y;
  const int j0 = blockIdx.x * 16;
  const float* Whh = dir ? WhhR : WhhF;
  const unsigned short* xW = dir ? xWR : xWF;
  int* flg = flags + dir * 512;

  __shared__ __align__(16) unsigned short hT[16][520];  // [b(+pad)][k] bf16
  __shared__ float gl[4][16][8];                        // [gate][jj][b]

  const int m = lane & 15, quad = lane >> 4;
  // preload A fragments: A[m=lane&15][k=quad*8+j] per 32-wide k-tile
  bf8_t afr[16];
  {
    const float* wr = Whh + ((long)(g * 512 + j0 + m)) * 512 + quad * 8;
#pragma unroll
    for (int kt = 0; kt < 16; ++kt) {
      float4 f0 = *(const float4*)(wr + kt * 32);
      float4 f1 = *(const float4*)(wr + kt * 32 + 4);
      bf8_t a;
      a[0] = (__bf16)f0.x; a[1] = (__bf16)f0.y; a[2] = (__bf16)f0.z; a[3] = (__bf16)f0.w;
      a[4] = (__bf16)f1.x; a[5] = (__bf16)f1.y; a[6] = (__bf16)f1.z; a[7] = (__bf16)f1.w;
      afr[kt] = a;
    }
  }
  for (int i = tid; i < 16 * 520; i += 256) (&hT[0][0])[i] = 0;
  float cstate = 0.f;  // valid for tid<128: jj=tid>>3, b=tid&7
  __syncthreads();

  for (int se = 0; se < 512; ++se) {
    const int s = dir ? 511 - se : se;
    if (se) {
      const int sp = dir ? s + 1 : s - 1;
      if (tid == 0) {
        while (__hip_atomic_load(flg + (se - 1), __ATOMIC_ACQUIRE,
                                 __HIP_MEMORY_SCOPE_AGENT) < 32) {
          __builtin_amdgcn_s_sleep(2);
        }
      }
      __syncthreads();
#pragma unroll
      for (int c = 0; c < 16; ++c) {
        int idx = c * 256 + tid;
        int bb = idx >> 9, j = idx & 511;
        float hv = out[((long)(bb * 512 + sp)) * 1024 + dir * 512 + j];
        hT[bb][j] = f2bf(hv);
      }
      __syncthreads();
    }
    // gates: D[m=jj][n=b] = sum_k Whh[g*512+j0+jj][k] * h_prev[b][k]
    f32x4 acc = {0.f, 0.f, 0.f, 0.f};
#pragma unroll
    for (int kt = 0; kt < 16; ++kt) {
      bf8_t bfr = *(const bf8_t*)&hT[m][kt * 32 + quad * 8];
      acc = __builtin_amdgcn_mfma_f32_16x16x32_bf16(afr[kt], bfr, acc, 0, 0, 0);
    }
    if (m < 8) {  // D col = lane&15 = b, rows = quad*4+r = jj
      long xo = ((long)(m * 512 + s)) * 2048 + g * 512 + j0 + quad * 4;
      uint2 u = *(const uint2*)(xW + xo);
      gl[g][quad * 4 + 0][m] = acc[0] + bflo(u.x);
      gl[g][quad * 4 + 1][m] = acc[1] + bfhi(u.x);
      gl[g][quad * 4 + 2][m] = acc[2] + bflo(u.y);
      gl[g][quad * 4 + 3][m] = acc[3] + bfhi(u.y);
    }
    __syncthreads();
    if (tid < 128) {
      const int jj = tid >> 3, bb = tid & 7;
      float iv = gl[0][jj][bb], fv = gl[1][jj][bb];
      float gv = gl[2][jj][bb], ov = gl[3][jj][bb];
      float is = 1.f / (1.f + __expf(-iv));
      float fs = 1.f / (1.f + __expf(-fv));
      float gt = tanhf(gv);
      float os = 1.f / (1.f + __expf(-ov));
      cstate = fs * cstate + is * gt;
      float hv = os * tanhf(cstate);
      out[((long)(bb * 512 + s)) * 1024 + dir * 512 + j0 + jj] = hv;
    }
    __threadfence();
    __syncthreads();
    if (tid == 0) {
      __hip_atomic_fetch_add(flg + se, 1, __ATOMIC_RELEASE, __HIP_MEMORY_SCOPE_AGENT);
    }
  }
}

// ---------------------------------------------------------------------------
// Launch. Workspace layout (MB offsets), lifetimes hand-verified:
//   [0,24)  qkv_b (qkv GEMM -> attention) | attn_tmp [0,16) (attn-out -> LN)
//           | xW_f bf16 [0,16) (xW GEMM -> lstm)
//   [16,24) h1_b (attn LN -> inter GEMM) | xW_r bf16 [16,32)
//   [24,40) h0_f (emb LN -> attn LN)     | inter_bf [24,48) (FFN)
//   [40,48) c2p_h (head loop)
//   [48,56) p2c_h (head loop)            | h1_f [48,64) (attn LN -> ffn LN)
//   [64,72) h0_b (emb LN -> qkv GEMM) -> ctx_b (attn -> attn-out GEMM)
//           -> h2_b (ffn LN -> xW GEMMs)
//   [72,78) weight-cast scratch (one weight at a time, stream-serialized)
//   [78,80) relemb_b  [80,82) poskey_b  [82,84) posq_b
//   [84,..) bias_qkv, bsum_f, bsum_r, flags
//   ffn fp32 temp lives in d_out (LSTM later overwrites all of d_out).
// Peak: 85 MB.
// ---------------------------------------------------------------------------
extern "C" void kernel_launch(void* const* d_in, const int* in_sizes, int n_in,
                              void* d_out, int out_size, void* d_ws, size_t ws_size,
                              hipStream_t stream) {
  const float* x         = (const float*)d_in[0];
  const float* pos_emb   = (const float*)d_in[1];
  const float* emb_ln_g  = (const float*)d_in[2];
  const float* emb_ln_b  = (const float*)d_in[3];
  const float* in_proj_w = (const float*)d_in[4];
  const float* q_bias    = (const float*)d_in[5];
  const float* v_bias    = (const float*)d_in[6];
  const float* rel_emb   = (const float*)d_in[7];
  const float* pos_proj_w   = (const float*)d_in[8];
  const float* pos_q_proj_w = (const float*)d_in[9];
  const float* pos_q_proj_b = (const float*)d_in[10];
  const float* attn_out_w = (const float*)d_in[11];
  const float* attn_out_b = (const float*)d_in[12];
  const float* attn_ln_g  = (const float*)d_in[13];
  const float* attn_ln_b  = (const float*)d_in[14];
  const float* inter_w    = (const float*)d_in[15];
  const float* inter_b    = (const float*)d_in[16];
  const float* ffn_out_w  = (const float*)d_in[17];
  const float* ffn_out_b  = (const float*)d_in[18];
  const float* ffn_ln_g   = (const float*)d_in[19];
  const float* ffn_ln_b   = (const float*)d_in[20];
  const float* Wih_f = (const float*)d_in[21];
  const float* Whh_f = (const float*)d_in[22];
  const float* bih_f = (const float*)d_in[23];
  const float* bhh_f = (const float*)d_in[24];
  const float* Wih_r = (const float*)d_in[25];
  const float* Whh_r = (const float*)d_in[26];
  const float* bih_r = (const float*)d_in[27];
  const float* bhh_r = (const float*)d_in[28];
  float* out = (float*)d_out;

  const size_t MB = 1ull << 20;
  const size_t NEED = 85 * MB;
  if (ws_size < NEED) {
    k_sentinel<<<dim3(1), dim3(1), 0, stream>>>(out);
    return;
  }
  char* ws = (char*)d_ws;
  typedef unsigned short u16;
  u16*   qkv_b    = (u16*)(ws + 0);
  float* attn_tmp = (float*)(ws + 0);
  u16*   xW_f     = (u16*)(ws + 0);
  u16*   h1_b     = (u16*)(ws + 16 * MB);
  u16*   xW_r     = (u16*)(ws + 16 * MB);
  float* h0_f     = (float*)(ws + 24 * MB);
  u16*   inter_bf = (u16*)(ws + 24 * MB);
  u16*   c2p_h    = (u16*)(ws + 40 * MB);
  u16*   p2c_h    = (u16*)(ws + 48 * MB);
  float* h1_f     = (float*)(ws + 48 * MB);
  u16*   h0_b     = (u16*)(ws + 64 * MB);
  u16*   ctx_b    = (u16*)(ws + 64 * MB);
  u16*   h2_b     = (u16*)(ws + 64 * MB);
  u16*   wscr     = (u16*)(ws + 72 * MB);
  u16*   relemb_b = (u16*)(ws + 78 * MB);
  u16*   poskey_b = (u16*)(ws + 80 * MB);
  u16*   posq_b   = (u16*)(ws + 82 * MB);
  float* bias_qkv = (float*)(ws + 84 * MB);
  float* bsum_f   = (float*)(ws + 84 * MB + 16 * 1024);
  float* bsum_r   = (float*)(ws + 84 * MB + 32 * 1024);
  int*   flags    = (int*)(ws + 84 * MB + 48 * 1024);
  float* ffn_tmp  = out;  // d_out as fp32 scratch; LSTM overwrites all of it

  const float SCALE = 0.051031036307982884f;  // 1/sqrt(128*3)

  hipMemsetAsync(flags, 0, 1024 * 4, stream);

  auto cast = [&](const float* src, u16* dst, long n) {
    k_cast_bf16<<<dim3((unsigned)(n / 1024)), dim3(256), 0, stream>>>(src, dst);
  };

  k_build_bias<<<dim3(12), dim3(256), 0, stream>>>(q_bias, v_bias, bias_qkv,
                                                   bih_f, bhh_f, bsum_f,
                                                   bih_r, bhh_r, bsum_r);

  // P1: embeddings LN: h0 = LN(x + pos_emb[s])
  k_layernorm<<<dim3(4096), dim3(256), 0, stream>>>(x, pos_emb, 511u, emb_ln_g,
                                                    emb_ln_b, h0_f, h0_b);

  // P2: qkv = h0 @ in_proj^T + (q_bias,0,v_bias)   [bf16]
  cast(in_proj_w, wscr, 3145728L);
  k_gemm_bt<1><<<dim3(24, 32), dim3(256), 0, stream>>>(
      h0_b, 1024, wscr, 1024, qkv_b, 3072, 1024, bias_qkv, 1.0f);

  // P3: pos_key = rel_emb @ pos_proj^T; pos_q = (rel_emb @ pos_q_proj^T + b)*scale
  cast(rel_emb, relemb_b, 1048576L);
  cast(pos_proj_w, wscr, 1048576L);
  k_gemm_bt<1><<<dim3(8, 8), dim3(256), 0, stream>>>(
      relemb_b, 1024, wscr, 1024, poskey_b, 1024, 1024, (const float*)nullptr, 1.0f);
  cast(pos_q_proj_w, wscr, 1048576L);
  k_gemm_bt<1><<<dim3(8, 8), dim3(256), 0, stream>>>(
      relemb_b, 1024, wscr, 1024, posq_b, 1024, 1024, pos_q_proj_b, SCALE);

  // P4: per-head: c2p_h, p2c_h (Toeplitz bases), attention
  for (int h = 0; h < 8; ++h) {
    k_gemm_bt<1><<<dim3(8, 32), dim3(256), 0, stream>>>(
        qkv_b + h * 128, 3072, poskey_b + h * 128, 1024, c2p_h, 1024, 128,
        (const float*)nullptr, SCALE);
    k_gemm_bt<1><<<dim3(8, 32), dim3(256), 0, stream>>>(
        qkv_b + 1024 + h * 128, 3072, posq_b + h * 128, 1024, p2c_h, 1024, 128,
        (const float*)nullptr, 1.0f);
    k_attention<<<dim3(32, 8), dim3(256), 0, stream>>>(qkv_b, c2p_h, p2c_h, ctx_b, h);
  }

  // P5: attn out projection (fp32) + LN(+h0) -> h1
  cast(attn_out_w, wscr, 1048576L);
  k_gemm_bt<0><<<dim3(8, 32), dim3(256), 0, stream>>>(
      ctx_b, 1024, wscr, 1024, attn_tmp, 1024, 1024, attn_out_b, 1.0f);
  k_layernorm<<<dim3(4096), dim3(256), 0, stream>>>(attn_tmp, h0_f, 0xFFFFFFFFu,
                                                    attn_ln_g, attn_ln_b, h1_f, h1_b);

  // P6: FFN
  cast(inter_w, wscr, 3145728L);
  k_gemm_bt<2><<<dim3(24, 32), dim3(256), 0, stream>>>(
      h1_b, 1024, wscr, 1024, inter_bf, 3072, 1024, inter_b, 1.0f);
  cast(ffn_out_w, wscr, 3145728L);
  k_gemm_bt<0><<<dim3(8, 32), dim3(256), 0, stream>>>(
      inter_bf, 3072, wscr, 3072, ffn_tmp, 1024, 3072, ffn_out_b, 1.0f);
  k_layernorm<<<dim3(4096), dim3(256), 0, stream>>>(ffn_tmp, h1_f, 0xFFFFFFFFu,
                                                    ffn_ln_g, ffn_ln_b,
                                                    (float*)nullptr, h2_b);

  // P7: LSTM input projections xW = h2 @ Wih^T + (bih+bhh)   [bf16]
  cast(Wih_f, wscr, 2097152L);
  k_gemm_bt<1><<<dim3(16, 32), dim3(256), 0, stream>>>(
      h2_b, 1024, wscr, 1024, xW_f, 2048, 1024, bsum_f, 1.0f);
  cast(Wih_r, wscr, 2097152L);
  k_gemm_bt<1><<<dim3(16, 32), dim3(256), 0, stream>>>(
      h2_b, 1024, wscr, 1024, xW_r, 2048, 1024, bsum_r, 1.0f);

  // P8: bidirectional LSTM recurrence -> writes d_out directly
  k_lstm<<<dim3(32, 2), dim3(256), 0, stream>>>(Whh_f, Whh_r, xW_f, xW_r, out, flags);

  (void)in_sizes; (void)n_in; (void)out_size;
}

// Round 3
// 2439.949 us; speedup vs baseline: 2.2004x; 2.2004x over previous
//
#include <hip/hip_runtime.h>
#include <cstdint>

// ---------------------------------------------------------------------------
// Problem constants: B=8, S=512, H=1024, NH=8, DH=128, INTER=3072, SPAN=512,
// LSTM_H=512. Output fp32 [B,S,H] = concat(hf, hr).
// ---------------------------------------------------------------------------

typedef __bf16 bf8_t __attribute__((ext_vector_type(8)));
typedef float f32x4 __attribute__((ext_vector_type(4)));
typedef unsigned int u32x4 __attribute__((ext_vector_type(4)));

__device__ __forceinline__ unsigned short f2bf(float f) {
  union { float f; unsigned int u; } v; v.f = f;
  unsigned int r = v.u + 0x7fffu + ((v.u >> 16) & 1u);
  return (unsigned short)(r >> 16);
}
__device__ __forceinline__ float bf2f(unsigned short s) {
  union { unsigned int u; float f; } v; v.u = ((unsigned int)s) << 16;
  return v.f;
}
__device__ __forceinline__ float bflo(unsigned int u) {
  union { unsigned int u; float f; } v; v.u = u << 16; return v.f;
}
__device__ __forceinline__ float bfhi(unsigned int u) {
  union { unsigned int u; float f; } v; v.u = u & 0xffff0000u; return v.f;
}

// async global->LDS, 16B per lane; lds dest is wave-uniform base + lane*16
__device__ __forceinline__ void async16(const void* g, void* l) {
  __builtin_amdgcn_global_load_lds(
      (const __attribute__((address_space(1))) void*)g,
      (__attribute__((address_space(3))) void*)l, 16, 0, 0);
}

// --- fine-grained IC-coherent (cross-XCD) memory ops: bypass L1/L2 ---------
__device__ __forceinline__ void ld2_ic(const unsigned short* p0,
                                       const unsigned short* p1,
                                       u32x4& r0, u32x4& r1) {
  asm volatile("global_load_dwordx4 %0, %2, off sc0 sc1\n\t"
               "global_load_dwordx4 %1, %3, off sc0 sc1\n\t"
               "s_waitcnt vmcnt(0)"
               : "=v"(r0), "=v"(r1)
               : "v"(p0), "v"(p1)
               : "memory");
}
__device__ __forceinline__ void st_ic(unsigned short* p, u32x4 v) {
  asm volatile("global_store_dwordx4 %0, %1, off sc0 sc1"
               :: "v"(p), "v"(v) : "memory");
}
__device__ __forceinline__ int ld_flag_ic(const int* p) {
  int r;
  asm volatile("global_load_dword %0, %1, off sc0 sc1\n\t"
               "s_waitcnt vmcnt(0)"
               : "=v"(r) : "v"(p) : "memory");
  return r;
}
__device__ __forceinline__ void wait_vm0() {
  asm volatile("s_waitcnt vmcnt(0)" ::: "memory");
}

// sentinel: ws_size too small -> make absmax unmistakably huge
__global__ void k_sentinel(float* out) { out[0] = 1e30f; }

// ---------------------------------------------------------------------------
// fp32 -> bf16 cast (n divisible by 1024)
// ---------------------------------------------------------------------------
__global__ void k_cast_bf16(const float* __restrict__ in, unsigned short* __restrict__ out) {
  long i = ((long)blockIdx.x * 256 + threadIdx.x) * 4;
  float4 v = *(const float4*)(in + i);
  unsigned int a = (unsigned int)f2bf(v.x) | ((unsigned int)f2bf(v.y) << 16);
  unsigned int b = (unsigned int)f2bf(v.z) | ((unsigned int)f2bf(v.w) << 16);
  *(uint2*)(out + i) = make_uint2(a, b);
}

// build qkv bias [3072] = (q_bias, 0, v_bias) and bsum = bih+bhh per dir
__global__ void k_build_bias(const float* qb, const float* vb, float* qkvBias,
                             const float* bihf, const float* bhhf, float* bsf,
                             const float* bihr, const float* bhhr, float* bsr) {
  int i = blockIdx.x * 256 + threadIdx.x;
  if (i < 3072) {
    float v;
    if (i < 1024) v = qb[i];
    else if (i < 2048) v = 0.f;
    else v = vb[i - 2048];
    qkvBias[i] = v;
  }
  if (i < 2048) {
    bsf[i] = bihf[i] + bhhf[i];
    bsr[i] = bihr[i] + bhhr[i];
  }
}

// ---------------------------------------------------------------------------
// LayerNorm over 1024 cols. in (+res) -> outF (fp32, optional) + outB (bf16,
// optional). res row index = row & resMask (mask=511 for pos_emb broadcast).
// ---------------------------------------------------------------------------
__global__ __launch_bounds__(256) void k_layernorm(
    const float* __restrict__ in, const float* __restrict__ res, unsigned int resMask,
    const float* __restrict__ gamma, const float* __restrict__ beta,
    float* __restrict__ outF, unsigned short* __restrict__ outB) {
  const int row = blockIdx.x;
  const int tid = threadIdx.x;
  float4 v = ((const float4*)(in + (long)row * 1024))[tid];
  if (res) {
    float4 r = ((const float4*)(res + (long)(row & resMask) * 1024))[tid];
    v.x += r.x; v.y += r.y; v.z += r.z; v.w += r.w;
  }
  float s = v.x + v.y + v.z + v.w;
  float q = v.x * v.x + v.y * v.y + v.z * v.z + v.w * v.w;
#pragma unroll
  for (int o = 32; o; o >>= 1) { s += __shfl_down(s, o); q += __shfl_down(q, o); }
  __shared__ float rs[4], rq[4];
  const int wave = tid >> 6, lane = tid & 63;
  if (lane == 0) { rs[wave] = s; rq[wave] = q; }
  __syncthreads();
  s = rs[0] + rs[1] + rs[2] + rs[3];
  q = rq[0] + rq[1] + rq[2] + rq[3];
  const float mean = s * (1.f / 1024.f);
  const float var = q * (1.f / 1024.f) - mean * mean;
  const float rstd = rsqrtf(var + 1e-7f);
  float4 g4 = ((const float4*)gamma)[tid];
  float4 b4 = ((const float4*)beta)[tid];
  float4 o4;
  o4.x = (v.x - mean) * rstd * g4.x + b4.x;
  o4.y = (v.y - mean) * rstd * g4.y + b4.y;
  o4.z = (v.z - mean) * rstd * g4.z + b4.z;
  o4.w = (v.w - mean) * rstd * g4.w + b4.w;
  if (outF) ((float4*)(outF + (long)row * 1024))[tid] = o4;
  if (outB) {
    unsigned int a = (unsigned int)f2bf(o4.x) | ((unsigned int)f2bf(o4.y) << 16);
    unsigned int b = (unsigned int)f2bf(o4.z) | ((unsigned int)f2bf(o4.w) << 16);
    ((uint2*)(outB + (long)row * 1024))[tid] = make_uint2(a, b);
  }
}

// ---------------------------------------------------------------------------
// bf16 MFMA GEMM: C[M,N] = A[M,K] @ B[N,K]^T, 128x128 tile, BK=32,
// global_load_lds staging (m93/m97 structure). Epilogue:
//   v = (acc + bias[col]) * scale;  MODE 0: fp32 store, 1: bf16, 2: gelu->bf16
// All of M,N multiples of 128; K multiple of 32.
// ---------------------------------------------------------------------------
template <int MODE>
__global__ __launch_bounds__(256) void k_gemm_bt(
    const unsigned short* __restrict__ A, int lda,
    const unsigned short* __restrict__ Bm, int ldb,
    void* __restrict__ Cv, int ldc,
    int K, const float* __restrict__ bias, float scale) {
  __shared__ __align__(16) unsigned short As[128 * 32];
  __shared__ __align__(16) unsigned short Bs[128 * 32];
  const int tid = threadIdx.x;
  const int lane = tid & 63;
  const int wave = tid >> 6;
  const int n0 = blockIdx.x * 128;
  const int m0 = blockIdx.y * 128;
  const int srow = tid >> 2;          // 0..63
  const int scol = (tid & 3) * 8;     // 0,8,16,24
  const unsigned short* ag0 = A + (long)(m0 + srow) * lda + scol;
  const unsigned short* ag1 = A + (long)(m0 + 64 + srow) * lda + scol;
  const unsigned short* bg0 = Bm + (long)(n0 + srow) * ldb + scol;
  const unsigned short* bg1 = Bm + (long)(n0 + 64 + srow) * ldb + scol;
  unsigned short* asd0 = &As[(wave * 16) * 32];        // wave-uniform LDS dest
  unsigned short* asd1 = &As[(64 + wave * 16) * 32];
  unsigned short* bsd0 = &Bs[(wave * 16) * 32];
  unsigned short* bsd1 = &Bs[(64 + wave * 16) * 32];
  const int wm = wave >> 1, wn = wave & 1;
  const int mrow = lane & 15;
  const int kq = (lane >> 4) * 8;
  const f32x4 vzero = {0.f, 0.f, 0.f, 0.f};
  f32x4 acc[4][4];
#pragma unroll
  for (int i = 0; i < 4; ++i)
#pragma unroll
    for (int j = 0; j < 4; ++j) acc[i][j] = vzero;

  const int nk = K >> 5;
  for (int kt = 0; kt < nk; ++kt) {
    if (kt) __syncthreads();        // previous tile consumed
    async16(ag0, asd0); async16(ag1, asd1);
    async16(bg0, bsd0); async16(bg1, bsd1);
    ag0 += 32; ag1 += 32; bg0 += 32; bg1 += 32;
    __syncthreads();                // drains vmcnt -> staged data visible
    bf8_t af[4], bf[4];
#pragma unroll
    for (int i = 0; i < 4; ++i)
      af[i] = *(const bf8_t*)&As[(wm * 64 + i * 16 + mrow) * 32 + kq];
#pragma unroll
    for (int j = 0; j < 4; ++j)
      bf[j] = *(const bf8_t*)&Bs[(wn * 64 + j * 16 + mrow) * 32 + kq];
#pragma unroll
    for (int i = 0; i < 4; ++i)
#pragma unroll
      for (int j = 0; j < 4; ++j)
        acc[i][j] = __builtin_amdgcn_mfma_f32_16x16x32_bf16(af[i], bf[j], acc[i][j], 0, 0, 0);
  }
  const int quad = lane >> 4;
  const int cn = lane & 15;
  float* Cf = (float*)Cv;
  unsigned short* Cb = (unsigned short*)Cv;
#pragma unroll
  for (int i = 0; i < 4; ++i) {
#pragma unroll
    for (int j = 0; j < 4; ++j) {
#pragma unroll
      for (int r = 0; r < 4; ++r) {
        int row = m0 + wm * 64 + i * 16 + quad * 4 + r;
        int col = n0 + wn * 64 + j * 16 + cn;
        float v = acc[i][j][r];
        if (bias) v += bias[col];
        v *= scale;
        if (MODE == 2) v = 0.5f * v * (1.0f + erff(v * 0.70710678118654752f));
        long idx = (long)row * ldc + col;
        if (MODE == 0) Cf[idx] = v;
        else Cb[idx] = f2bf(v);
      }
    }
  }
}

// ---------------------------------------------------------------------------
// Attention core, one head per launch. Per (b, 16-row q-tile):
// scores = qk*scale + c2p + p2c; softmax; ctx = probs @ v.
//   c2p_h[b*512+q][rel], p2c_h[b*512+k][rel], rel = q-k+512 (clip is no-op).
// ---------------------------------------------------------------------------
__global__ __launch_bounds__(256) void k_attention(
    const unsigned short* __restrict__ qkv,
    const unsigned short* __restrict__ c2p,
    const unsigned short* __restrict__ p2c,
    unsigned short* __restrict__ ctx, int h) {
  const int tid = threadIdx.x;
  const int qt = blockIdx.x;   // 0..31
  const int b = blockIdx.y;    // 0..7
  const int q0 = qt * 16;
  __shared__ __align__(16) float sc[16][520];
  __shared__ __align__(16) float qs[16][128];

  // load q tile (biased, unscaled)
  for (int i = tid; i < 16 * 128; i += 256) {
    int ql = i >> 7, d = i & 127;
    qs[ql][d] = bf2f(qkv[((long)(b * 512 + q0 + ql)) * 3072 + h * 128 + d]);
  }
  __syncthreads();

  const float scale = 0.051031036307982884f;  // 1/sqrt(128*3)
  for (int pass = 0; pass < 2; ++pass) {
    const int k = tid + pass * 256;
    float4 kvf[32];
    const unsigned short* kp = qkv + ((long)(b * 512 + k)) * 3072 + 1024 + h * 128;
#pragma unroll
    for (int c = 0; c < 16; ++c) {
      uint4 u = ((const uint4*)kp)[c];
      kvf[2 * c + 0] = make_float4(bflo(u.x), bfhi(u.x), bflo(u.y), bfhi(u.y));
      kvf[2 * c + 1] = make_float4(bflo(u.z), bfhi(u.z), bflo(u.w), bfhi(u.w));
    }
    // p2c: row = b*512+k, col = (q0+ql)-k+512 -> contiguous in ql
    const unsigned short* pp = p2c + ((long)(b * 512 + k)) * 1024 + (q0 - k + 512);
    for (int ql = 0; ql < 16; ++ql) {
      float dot = 0.f;
#pragma unroll
      for (int dd = 0; dd < 32; ++dd) {
        float4 qf = ((const float4*)&qs[ql][0])[dd];
        dot += qf.x * kvf[dd].x + qf.y * kvf[dd].y + qf.z * kvf[dd].z + qf.w * kvf[dd].w;
      }
      sc[ql][k] = dot * scale + bf2f(pp[ql]);
    }
  }
  __syncthreads();

  // softmax rows (+ c2p add, contiguous per row: col = q - k + 512)
  const int wave = tid >> 6, lane = tid & 63;
#pragma unroll
  for (int rr = 0; rr < 4; ++rr) {
    const int r = wave * 4 + rr;
    const int q = q0 + r;
    const unsigned short* cp = c2p + ((long)(b * 512 + q)) * 1024 + (q + 512);
    float v[8];
#pragma unroll
    for (int i = 0; i < 8; ++i) {
      int k = lane + 64 * i;
      v[i] = sc[r][k] + bf2f(cp[-k]);
    }
    float m = v[0];
#pragma unroll
    for (int i = 1; i < 8; ++i) m = fmaxf(m, v[i]);
#pragma unroll
    for (int o = 32; o; o >>= 1) m = fmaxf(m, __shfl_xor(m, o));
    float ssum = 0.f;
#pragma unroll
    for (int i = 0; i < 8; ++i) { v[i] = __expf(v[i] - m); ssum += v[i]; }
#pragma unroll
    for (int o = 32; o; o >>= 1) ssum += __shfl_xor(ssum, o);
    const float inv = 1.0f / ssum;
#pragma unroll
    for (int i = 0; i < 8; ++i) sc[r][lane + 64 * i] = v[i] * inv;
  }
  __syncthreads();

  // ctx = probs @ v
  const int d = tid & 127;
  const int qg = tid >> 7;  // 0..1
  float acc[8] = {0, 0, 0, 0, 0, 0, 0, 0};
  const unsigned short* vp = qkv + ((long)(b * 512)) * 3072 + 2048 + h * 128 + d;
  for (int k = 0; k < 512; k += 4) {
    float v0 = bf2f(vp[(long)(k + 0) * 3072]);
    float v1 = bf2f(vp[(long)(k + 1) * 3072]);
    float v2 = bf2f(vp[(long)(k + 2) * 3072]);
    float v3 = bf2f(vp[(long)(k + 3) * 3072]);
#pragma unroll
    for (int qq = 0; qq < 8; ++qq) {
      float4 p = *(const float4*)&sc[qg * 8 + qq][k];
      acc[qq] += p.x * v0 + p.y * v1 + p.z * v2 + p.w * v3;
    }
  }
#pragma unroll
  for (int qq = 0; qq < 8; ++qq) {
    int q = q0 + qg * 8 + qq;
    ctx[((long)(b * 512 + q)) * 1024 + h * 128 + d] = f2bf(acc[qq]);
  }
}

// ---------------------------------------------------------------------------
// Bidirectional LSTM recurrence, fence-free fine-grained sync.
// Grid (32, 2): 32 blocks per direction (all co-resident). Block owns 16
// hidden channels x 4 gates = 64 Whh rows as persistent MFMA A-fragments
// (wave g = gate g). Exchange of h between blocks goes through an 8KB/step
// bf16 buffer hx using sc0/sc1 (IC-coherent, bypasses non-coherent L2s);
// ordering = per-wave s_waitcnt vmcnt(0) + barrier + RELAXED agent atomic
// flag. NO acquire/release fences -> no L2 invalidate/writeback storms
// (round-2 version: 8us/step, 99% stalled in cache maintenance).
// Gate order i,f,g,o (torch). xW is bf16 [B][S][4*512].
// ---------------------------------------------------------------------------
__global__ __launch_bounds__(256) void k_lstm(
    const float* __restrict__ WhhF, const float* __restrict__ WhhR,
    const unsigned short* __restrict__ xWF, const unsigned short* __restrict__ xWR,
    float* __restrict__ out, unsigned short* __restrict__ hx,
    int* __restrict__ flags) {
  const int tid = threadIdx.x;
  const int lane = tid & 63;
  const int g = tid >> 6;              // wave index = gate
  const int dir = blockIdx.y;
  const int j0 = blockIdx.x * 16;
  const float* Whh = dir ? WhhR : WhhF;
  const unsigned short* xW = dir ? xWR : xWF;
  int* flg = flags + dir * 512;
  unsigned short* hxd = hx + (long)dir * 512 * 8 * 512;  // [s][b][512]

  __shared__ __align__(16) unsigned short hT[16][520];  // [b(+pad)][k] bf16
  __shared__ float gl[4][16][8];                        // [gate][jj][b]
  __shared__ __align__(16) unsigned short hs[8][16];    // staging [b][jj]

  const int m = lane & 15, quad = lane >> 4;
  // preload A fragments: A[m=lane&15][k=quad*8+j] per 32-wide k-tile
  bf8_t afr[16];
  {
    const float* wr = Whh + ((long)(g * 512 + j0 + m)) * 512 + quad * 8;
#pragma unroll
    for (int kt = 0; kt < 16; ++kt) {
      float4 f0 = *(const float4*)(wr + kt * 32);
      float4 f1 = *(const float4*)(wr + kt * 32 + 4);
      bf8_t a;
      a[0] = (__bf16)f0.x; a[1] = (__bf16)f0.y; a[2] = (__bf16)f0.z; a[3] = (__bf16)f0.w;
      a[4] = (__bf16)f1.x; a[5] = (__bf16)f1.y; a[6] = (__bf16)f1.z; a[7] = (__bf16)f1.w;
      afr[kt] = a;
    }
  }
  for (int i = tid; i < 16 * 520; i += 256) (&hT[0][0])[i] = 0;
  float cstate = 0.f;  // valid for tid<128: jj=tid>>3, b=tid&7
  __syncthreads();

  for (int se = 0; se < 512; ++se) {
    const int s = dir ? 511 - se : se;
    // prefetch xW for this step (independent of h_prev)
    uint2 uxw = make_uint2(0u, 0u);
    if (m < 8)
      uxw = *(const uint2*)(xW + ((long)(m * 512 + s)) * 2048 + g * 512 + j0 + quad * 4);

    if (se) {
      const int sp = dir ? s + 1 : s - 1;
      if (tid == 0) {
        while (ld_flag_ic(flg + (se - 1)) < 32) __builtin_amdgcn_s_sleep(1);
      }
      __syncthreads();
      // load h_prev (4096 bf16 = 8KB) from IC: 2 x dwordx4 per thread
      const unsigned short* hxs = hxd + (long)sp * 4096;
      const int bb = tid >> 6;              // 0..3
      const int jc = (tid & 63) * 8;        // 0..504
      u32x4 r0, r1;
      ld2_ic(hxs + bb * 512 + jc, hxs + (bb + 4) * 512 + jc, r0, r1);
      *(u32x4*)&hT[bb][jc] = r0;
      *(u32x4*)&hT[bb + 4][jc] = r1;
      __syncthreads();
    }

    // gates: D[m=jj][n=b] = sum_k Whh[g*512+j0+jj][k] * h_prev[b][k]
    f32x4 acc0 = {0.f, 0.f, 0.f, 0.f}, acc1 = {0.f, 0.f, 0.f, 0.f};
#pragma unroll
    for (int t = 0; t < 8; ++t) {
      bf8_t b0 = *(const bf8_t*)&hT[m][(2 * t) * 32 + quad * 8];
      bf8_t b1 = *(const bf8_t*)&hT[m][(2 * t + 1) * 32 + quad * 8];
      acc0 = __builtin_amdgcn_mfma_f32_16x16x32_bf16(afr[2 * t], b0, acc0, 0, 0, 0);
      acc1 = __builtin_amdgcn_mfma_f32_16x16x32_bf16(afr[2 * t + 1], b1, acc1, 0, 0, 0);
    }
    if (m < 8) {  // D col = lane&15 = b, rows = quad*4+r = jj
      gl[g][quad * 4 + 0][m] = acc0[0] + acc1[0] + bflo(uxw.x);
      gl[g][quad * 4 + 1][m] = acc0[1] + acc1[1] + bfhi(uxw.x);
      gl[g][quad * 4 + 2][m] = acc0[2] + acc1[2] + bflo(uxw.y);
      gl[g][quad * 4 + 3][m] = acc0[3] + acc1[3] + bfhi(uxw.y);
    }
    __syncthreads();
    if (tid < 128) {
      const int jj = tid >> 3, bb = tid & 7;
      float iv = gl[0][jj][bb], fv = gl[1][jj][bb];
      float gv = gl[2][jj][bb], ov = gl[3][jj][bb];
      float is = 1.f / (1.f + __expf(-iv));
      float fs = 1.f / (1.f + __expf(-fv));
      float gt = tanhf(gv);
      float os = 1.f / (1.f + __expf(-ov));
      cstate = fs * cstate + is * gt;
      float hv = os * tanhf(cstate);
      out[((long)(bb * 512 + s)) * 1024 + dir * 512 + j0 + jj] = hv;  // final fp32
      hs[bb][jj] = f2bf(hv);                                          // exchange bf16
    }
    __syncthreads();
    if (tid < 16) {  // publish 16B chunks to IC: [b][j0..j0+15]
      const int b = tid >> 1, half = tid & 1;
      st_ic(hxd + (long)s * 4096 + b * 512 + j0 + half * 8,
            *(const u32x4*)&hs[b][half * 8]);
    }
    wait_vm0();          // per-wave: all stores (out + hx) acked
    __syncthreads();     // all waves drained before flag
    if (tid == 0)
      __hip_atomic_fetch_add(flg + se, 1, __ATOMIC_RELAXED, __HIP_MEMORY_SCOPE_AGENT);
  }
}

// ---------------------------------------------------------------------------
// Launch. Workspace layout (MB offsets), lifetimes hand-verified:
//   [0,24)  qkv_b (qkv GEMM -> attention) | attn_tmp [0,16) (attn-out -> LN)
//           | xW_f bf16 [0,16) (xW GEMM -> lstm)
//   [16,24) h1_b (attn LN -> inter GEMM) | xW_r bf16 [16,32)
//   [24,40) h0_f (emb LN -> attn LN)     | inter_bf [24,48) (FFN)
//           | hx [32,40) (lstm h exchange, 8MB)
//   [40,48) c2p_h (head loop)
//   [48,56) p2c_h (head loop)            | h1_f [48,64) (attn LN -> ffn LN)
//   [64,72) h0_b (emb LN -> qkv GEMM) -> ctx_b (attn -> attn-out GEMM)
//           -> h2_b (ffn LN -> xW GEMMs)
//   [72,78) weight-cast scratch (one weight at a time, stream-serialized)
//   [78,80) relemb_b  [80,82) poskey_b  [82,84) posq_b
//   [84,..) bias_qkv, bsum_f, bsum_r, flags
//   ffn fp32 temp lives in d_out (LSTM later overwrites all of d_out).
// Peak: 85 MB.
// ---------------------------------------------------------------------------
extern "C" void kernel_launch(void* const* d_in, const int* in_sizes, int n_in,
                              void* d_out, int out_size, void* d_ws, size_t ws_size,
                              hipStream_t stream) {
  const float* x         = (const float*)d_in[0];
  const float* pos_emb   = (const float*)d_in[1];
  const float* emb_ln_g  = (const float*)d_in[2];
  const float* emb_ln_b  = (const float*)d_in[3];
  const float* in_proj_w = (const float*)d_in[4];
  const float* q_bias    = (const float*)d_in[5];
  const float* v_bias    = (const float*)d_in[6];
  const float* rel_emb   = (const float*)d_in[7];
  const float* pos_proj_w   = (const float*)d_in[8];
  const float* pos_q_proj_w = (const float*)d_in[9];
  const float* pos_q_proj_b = (const float*)d_in[10];
  const float* attn_out_w = (const float*)d_in[11];
  const float* attn_out_b = (const float*)d_in[12];
  const float* attn_ln_g  = (const float*)d_in[13];
  const float* attn_ln_b  = (const float*)d_in[14];
  const float* inter_w    = (const float*)d_in[15];
  const float* inter_b    = (const float*)d_in[16];
  const float* ffn_out_w  = (const float*)d_in[17];
  const float* ffn_out_b  = (const float*)d_in[18];
  const float* ffn_ln_g   = (const float*)d_in[19];
  const float* ffn_ln_b   = (const float*)d_in[20];
  const float* Wih_f = (const float*)d_in[21];
  const float* Whh_f = (const float*)d_in[22];
  const float* bih_f = (const float*)d_in[23];
  const float* bhh_f = (const float*)d_in[24];
  const float* Wih_r = (const float*)d_in[25];
  const float* Whh_r = (const float*)d_in[26];
  const float* bih_r = (const float*)d_in[27];
  const float* bhh_r = (const float*)d_in[28];
  float* out = (float*)d_out;

  const size_t MB = 1ull << 20;
  const size_t NEED = 85 * MB;
  if (ws_size < NEED) {
    k_sentinel<<<dim3(1), dim3(1), 0, stream>>>(out);
    return;
  }
  char* ws = (char*)d_ws;
  typedef unsigned short u16;
  u16*   qkv_b    = (u16*)(ws + 0);
  float* attn_tmp = (float*)(ws + 0);
  u16*   xW_f     = (u16*)(ws + 0);
  u16*   h1_b     = (u16*)(ws + 16 * MB);
  u16*   xW_r     = (u16*)(ws + 16 * MB);
  float* h0_f     = (float*)(ws + 24 * MB);
  u16*   inter_bf = (u16*)(ws + 24 * MB);
  u16*   hx       = (u16*)(ws + 32 * MB);
  u16*   c2p_h    = (u16*)(ws + 40 * MB);
  u16*   p2c_h    = (u16*)(ws + 48 * MB);
  float* h1_f     = (float*)(ws + 48 * MB);
  u16*   h0_b     = (u16*)(ws + 64 * MB);
  u16*   ctx_b    = (u16*)(ws + 64 * MB);
  u16*   h2_b     = (u16*)(ws + 64 * MB);
  u16*   wscr     = (u16*)(ws + 72 * MB);
  u16*   relemb_b = (u16*)(ws + 78 * MB);
  u16*   poskey_b = (u16*)(ws + 80 * MB);
  u16*   posq_b   = (u16*)(ws + 82 * MB);
  float* bias_qkv = (float*)(ws + 84 * MB);
  float* bsum_f   = (float*)(ws + 84 * MB + 16 * 1024);
  float* bsum_r   = (float*)(ws + 84 * MB + 32 * 1024);
  int*   flags    = (int*)(ws + 84 * MB + 48 * 1024);
  float* ffn_tmp  = out;  // d_out as fp32 scratch; LSTM overwrites all of it

  const float SCALE = 0.051031036307982884f;  // 1/sqrt(128*3)

  hipMemsetAsync(flags, 0, 1024 * 4, stream);

  auto cast = [&](const float* src, u16* dst, long n) {
    k_cast_bf16<<<dim3((unsigned)(n / 1024)), dim3(256), 0, stream>>>(src, dst);
  };

  k_build_bias<<<dim3(12), dim3(256), 0, stream>>>(q_bias, v_bias, bias_qkv,
                                                   bih_f, bhh_f, bsum_f,
                                                   bih_r, bhh_r, bsum_r);

  // P1: embeddings LN: h0 = LN(x + pos_emb[s])
  k_layernorm<<<dim3(4096), dim3(256), 0, stream>>>(x, pos_emb, 511u, emb_ln_g,
                                                    emb_ln_b, h0_f, h0_b);

  // P2: qkv = h0 @ in_proj^T + (q_bias,0,v_bias)   [bf16]
  cast(in_proj_w, wscr, 3145728L);
  k_gemm_bt<1><<<dim3(24, 32), dim3(256), 0, stream>>>(
      h0_b, 1024, wscr, 1024, qkv_b, 3072, 1024, bias_qkv, 1.0f);

  // P3: pos_key = rel_emb @ pos_proj^T; pos_q = (rel_emb @ pos_q_proj^T + b)*scale
  cast(rel_emb, relemb_b, 1048576L);
  cast(pos_proj_w, wscr, 1048576L);
  k_gemm_bt<1><<<dim3(8, 8), dim3(256), 0, stream>>>(
      relemb_b, 1024, wscr, 1024, poskey_b, 1024, 1024, (const float*)nullptr, 1.0f);
  cast(pos_q_proj_w, wscr, 1048576L);
  k_gemm_bt<1><<<dim3(8, 8), dim3(256), 0, stream>>>(
      relemb_b, 1024, wscr, 1024, posq_b, 1024, 1024, pos_q_proj_b, SCALE);

  // P4: per-head: c2p_h, p2c_h (Toeplitz bases), attention
  for (int h = 0; h < 8; ++h) {
    k_gemm_bt<1><<<dim3(8, 32), dim3(256), 0, stream>>>(
        qkv_b + h * 128, 3072, poskey_b + h * 128, 1024, c2p_h, 1024, 128,
        (const float*)nullptr, SCALE);
    k_gemm_bt<1><<<dim3(8, 32), dim3(256), 0, stream>>>(
        qkv_b + 1024 + h * 128, 3072, posq_b + h * 128, 1024, p2c_h, 1024, 128,
        (const float*)nullptr, 1.0f);
    k_attention<<<dim3(32, 8), dim3(256), 0, stream>>>(qkv_b, c2p_h, p2c_h, ctx_b, h);
  }

  // P5: attn out projection (fp32) + LN(+h0) -> h1
  cast(attn_out_w, wscr, 1048576L);
  k_gemm_bt<0><<<dim3(8, 32), dim3(256), 0, stream>>>(
      ctx_b, 1024, wscr, 1024, attn_tmp, 1024, 1024, attn_out_b, 1.0f);
  k_layernorm<<<dim3(4096), dim3(256), 0, stream>>>(attn_tmp, h0_f, 0xFFFFFFFFu,
                                                    attn_ln_g, attn_ln_b, h1_f, h1_b);

  // P6: FFN
  cast(inter_w, wscr, 3145728L);
  k_gemm_bt<2><<<dim3(24, 32), dim3(256), 0, stream>>>(
      h1_b, 1024, wscr, 1024, inter_bf, 3072, 1024, inter_b, 1.0f);
  cast(ffn_out_w, wscr, 3145728L);
  k_gemm_bt<0><<<dim3(8, 32), dim3(256), 0, stream>>>(
      inter_bf, 3072, wscr, 3072, ffn_tmp, 1024, 3072, ffn_out_b, 1.0f);
  k_layernorm<<<dim3(4096), dim3(256), 0, stream>>>(ffn_tmp, h1_f, 0xFFFFFFFFu,
                                                    ffn_ln_g, ffn_ln_b,
                                                    (float*)nullptr, h2_b);

  // P7: LSTM input projections xW = h2 @ Wih^T + (bih+bhh)   [bf16]
  cast(Wih_f, wscr, 2097152L);
  k_gemm_bt<1><<<dim3(16, 32), dim3(256), 0, stream>>>(
      h2_b, 1024, wscr, 1024, xW_f, 2048, 1024, bsum_f, 1.0f);
  cast(Wih_r, wscr, 2097152L);
  k_gemm_bt<1><<<dim3(16, 32), dim3(256), 0, stream>>>(
      h2_b, 1024, wscr, 1024, xW_r, 2048, 1024, bsum_r, 1.0f);

  // P8: bidirectional LSTM recurrence -> writes d_out directly
  k_lstm<<<dim3(32, 2), dim3(256), 0, stream>>>(Whh_f, Whh_r, xW_f, xW_r, out, hx, flags);

  (void)in_sizes; (void)n_in; (void)out_size;
}

// Round 4
// 2312.373 us; speedup vs baseline: 2.3218x; 1.0552x over previous
//
#include <hip/hip_runtime.h>
#include <cstdint>

// ---------------------------------------------------------------------------
// Problem constants: B=8, S=512, H=1024, NH=8, DH=128, INTER=3072, SPAN=512,
// LSTM_H=512. Output fp32 [B,S,H] = concat(hf, hr).
// ---------------------------------------------------------------------------

typedef __bf16 bf8_t __attribute__((ext_vector_type(8)));
typedef float f32x4 __attribute__((ext_vector_type(4)));
typedef unsigned int u32x4 __attribute__((ext_vector_type(4)));

__device__ __forceinline__ unsigned short f2bf(float f) {
  union { float f; unsigned int u; } v; v.f = f;
  unsigned int r = v.u + 0x7fffu + ((v.u >> 16) & 1u);
  return (unsigned short)(r >> 16);
}
__device__ __forceinline__ float bf2f(unsigned short s) {
  union { unsigned int u; float f; } v; v.u = ((unsigned int)s) << 16;
  return v.f;
}
__device__ __forceinline__ float bflo(unsigned int u) {
  union { unsigned int u; float f; } v; v.u = u << 16; return v.f;
}
__device__ __forceinline__ float bfhi(unsigned int u) {
  union { unsigned int u; float f; } v; v.u = u & 0xffff0000u; return v.f;
}

// async global->LDS, 16B per lane; lds dest is wave-uniform base + lane*16
__device__ __forceinline__ void async16(const void* g, void* l) {
  __builtin_amdgcn_global_load_lds(
      (const __attribute__((address_space(1))) void*)g,
      (__attribute__((address_space(3))) void*)l, 16, 0, 0);
}

// --- fine-grained IC-coherent (cross-XCD) memory ops: bypass L1/L2 ---------
__device__ __forceinline__ void ld2_ic(const unsigned short* p0,
                                       const unsigned short* p1,
                                       u32x4& r0, u32x4& r1) {
  asm volatile("global_load_dwordx4 %0, %2, off sc0 sc1\n\t"
               "global_load_dwordx4 %1, %3, off sc0 sc1\n\t"
               "s_waitcnt vmcnt(0)"
               : "=v"(r0), "=v"(r1)
               : "v"(p0), "v"(p1)
               : "memory");
}
__device__ __forceinline__ void st_ic(unsigned short* p, u32x4 v) {
  asm volatile("global_store_dwordx4 %0, %1, off sc0 sc1"
               :: "v"(p), "v"(v) : "memory");
}

// sentinel: ws_size too small -> make absmax unmistakably huge
__global__ void k_sentinel(float* out) { out[0] = 1e30f; }

// ---------------------------------------------------------------------------
// fp32 -> bf16 cast (n divisible by 1024)
// ---------------------------------------------------------------------------
__global__ void k_cast_bf16(const float* __restrict__ in, unsigned short* __restrict__ out) {
  long i = ((long)blockIdx.x * 256 + threadIdx.x) * 4;
  float4 v = *(const float4*)(in + i);
  unsigned int a = (unsigned int)f2bf(v.x) | ((unsigned int)f2bf(v.y) << 16);
  unsigned int b = (unsigned int)f2bf(v.z) | ((unsigned int)f2bf(v.w) << 16);
  *(uint2*)(out + i) = make_uint2(a, b);
}

// build qkv bias [3072] = (q_bias, 0, v_bias) and bsum = bih+bhh per dir
__global__ void k_build_bias(const float* qb, const float* vb, float* qkvBias,
                             const float* bihf, const float* bhhf, float* bsf,
                             const float* bihr, const float* bhhr, float* bsr) {
  int i = blockIdx.x * 256 + threadIdx.x;
  if (i < 3072) {
    float v;
    if (i < 1024) v = qb[i];
    else if (i < 2048) v = 0.f;
    else v = vb[i - 2048];
    qkvBias[i] = v;
  }
  if (i < 2048) {
    bsf[i] = bihf[i] + bhhf[i];
    bsr[i] = bihr[i] + bhhr[i];
  }
}

// ---------------------------------------------------------------------------
// LayerNorm over 1024 cols. in (+res) -> outF (fp32, optional) + outB (bf16,
// optional). res row index = row & resMask (mask=511 for pos_emb broadcast).
// ---------------------------------------------------------------------------
__global__ __launch_bounds__(256) void k_layernorm(
    const float* __restrict__ in, const float* __restrict__ res, unsigned int resMask,
    const float* __restrict__ gamma, const float* __restrict__ beta,
    float* __restrict__ outF, unsigned short* __restrict__ outB) {
  const int row = blockIdx.x;
  const int tid = threadIdx.x;
  float4 v = ((const float4*)(in + (long)row * 1024))[tid];
  if (res) {
    float4 r = ((const float4*)(res + (long)(row & resMask) * 1024))[tid];
    v.x += r.x; v.y += r.y; v.z += r.z; v.w += r.w;
  }
  float s = v.x + v.y + v.z + v.w;
  float q = v.x * v.x + v.y * v.y + v.z * v.z + v.w * v.w;
#pragma unroll
  for (int o = 32; o; o >>= 1) { s += __shfl_down(s, o); q += __shfl_down(q, o); }
  __shared__ float rs[4], rq[4];
  const int wave = tid >> 6, lane = tid & 63;
  if (lane == 0) { rs[wave] = s; rq[wave] = q; }
  __syncthreads();
  s = rs[0] + rs[1] + rs[2] + rs[3];
  q = rq[0] + rq[1] + rq[2] + rq[3];
  const float mean = s * (1.f / 1024.f);
  const float var = q * (1.f / 1024.f) - mean * mean;
  const float rstd = rsqrtf(var + 1e-7f);
  float4 g4 = ((const float4*)gamma)[tid];
  float4 b4 = ((const float4*)beta)[tid];
  float4 o4;
  o4.x = (v.x - mean) * rstd * g4.x + b4.x;
  o4.y = (v.y - mean) * rstd * g4.y + b4.y;
  o4.z = (v.z - mean) * rstd * g4.z + b4.z;
  o4.w = (v.w - mean) * rstd * g4.w + b4.w;
  if (outF) ((float4*)(outF + (long)row * 1024))[tid] = o4;
  if (outB) {
    unsigned int a = (unsigned int)f2bf(o4.x) | ((unsigned int)f2bf(o4.y) << 16);
    unsigned int b = (unsigned int)f2bf(o4.z) | ((unsigned int)f2bf(o4.w) << 16);
    ((uint2*)(outB + (long)row * 1024))[tid] = make_uint2(a, b);
  }
}

// ---------------------------------------------------------------------------
// bf16 MFMA GEMM: C[M,N] = A[M,K] @ B[N,K]^T, 128x128 tile, BK=32,
// global_load_lds staging (m93/m97 structure). Epilogue:
//   v = (acc + bias[col]) * scale;  MODE 0: fp32 store, 1: bf16, 2: gelu->bf16
// All of M,N multiples of 128; K multiple of 32.
// ---------------------------------------------------------------------------
template <int MODE>
__global__ __launch_bounds__(256) void k_gemm_bt(
    const unsigned short* __restrict__ A, int lda,
    const unsigned short* __restrict__ Bm, int ldb,
    void* __restrict__ Cv, int ldc,
    int K, const float* __restrict__ bias, float scale) {
  __shared__ __align__(16) unsigned short As[128 * 32];
  __shared__ __align__(16) unsigned short Bs[128 * 32];
  const int tid = threadIdx.x;
  const int lane = tid & 63;
  const int wave = tid >> 6;
  const int n0 = blockIdx.x * 128;
  const int m0 = blockIdx.y * 128;
  const int srow = tid >> 2;          // 0..63
  const int scol = (tid & 3) * 8;     // 0,8,16,24
  const unsigned short* ag0 = A + (long)(m0 + srow) * lda + scol;
  const unsigned short* ag1 = A + (long)(m0 + 64 + srow) * lda + scol;
  const unsigned short* bg0 = Bm + (long)(n0 + srow) * ldb + scol;
  const unsigned short* bg1 = Bm + (long)(n0 + 64 + srow) * ldb + scol;
  unsigned short* asd0 = &As[(wave * 16) * 32];        // wave-uniform LDS dest
  unsigned short* asd1 = &As[(64 + wave * 16) * 32];
  unsigned short* bsd0 = &Bs[(wave * 16) * 32];
  unsigned short* bsd1 = &Bs[(64 + wave * 16) * 32];
  const int wm = wave >> 1, wn = wave & 1;
  const int mrow = lane & 15;
  const int kq = (lane >> 4) * 8;
  const f32x4 vzero = {0.f, 0.f, 0.f, 0.f};
  f32x4 acc[4][4];
#pragma unroll
  for (int i = 0; i < 4; ++i)
#pragma unroll
    for (int j = 0; j < 4; ++j) acc[i][j] = vzero;

  const int nk = K >> 5;
  for (int kt = 0; kt < nk; ++kt) {
    if (kt) __syncthreads();        // previous tile consumed
    async16(ag0, asd0); async16(ag1, asd1);
    async16(bg0, bsd0); async16(bg1, bsd1);
    ag0 += 32; ag1 += 32; bg0 += 32; bg1 += 32;
    __syncthreads();                // drains vmcnt -> staged data visible
    bf8_t af[4], bf[4];
#pragma unroll
    for (int i = 0; i < 4; ++i)
      af[i] = *(const bf8_t*)&As[(wm * 64 + i * 16 + mrow) * 32 + kq];
#pragma unroll
    for (int j = 0; j < 4; ++j)
      bf[j] = *(const bf8_t*)&Bs[(wn * 64 + j * 16 + mrow) * 32 + kq];
#pragma unroll
    for (int i = 0; i < 4; ++i)
#pragma unroll
      for (int j = 0; j < 4; ++j)
        acc[i][j] = __builtin_amdgcn_mfma_f32_16x16x32_bf16(af[i], bf[j], acc[i][j], 0, 0, 0);
  }
  const int quad = lane >> 4;
  const int cn = lane & 15;
  float* Cf = (float*)Cv;
  unsigned short* Cb = (unsigned short*)Cv;
#pragma unroll
  for (int i = 0; i < 4; ++i) {
#pragma unroll
    for (int j = 0; j < 4; ++j) {
#pragma unroll
      for (int r = 0; r < 4; ++r) {
        int row = m0 + wm * 64 + i * 16 + quad * 4 + r;
        int col = n0 + wn * 64 + j * 16 + cn;
        float v = acc[i][j][r];
        if (bias) v += bias[col];
        v *= scale;
        if (MODE == 2) v = 0.5f * v * (1.0f + erff(v * 0.70710678118654752f));
        long idx = (long)row * ldc + col;
        if (MODE == 0) Cf[idx] = v;
        else Cb[idx] = f2bf(v);
      }
    }
  }
}

// ---------------------------------------------------------------------------
// Attention core, one head per launch. Per (b, 16-row q-tile):
// scores = qk*scale + c2p + p2c; softmax; ctx = probs @ v.
//   c2p_h[b*512+q][rel], p2c_h[b*512+k][rel], rel = q-k+512 (clip is no-op).
// ---------------------------------------------------------------------------
__global__ __launch_bounds__(256) void k_attention(
    const unsigned short* __restrict__ qkv,
    const unsigned short* __restrict__ c2p,
    const unsigned short* __restrict__ p2c,
    unsigned short* __restrict__ ctx, int h) {
  const int tid = threadIdx.x;
  const int qt = blockIdx.x;   // 0..31
  const int b = blockIdx.y;    // 0..7
  const int q0 = qt * 16;
  __shared__ __align__(16) float sc[16][520];
  __shared__ __align__(16) float qs[16][128];

  // load q tile (biased, unscaled)
  for (int i = tid; i < 16 * 128; i += 256) {
    int ql = i >> 7, d = i & 127;
    qs[ql][d] = bf2f(qkv[((long)(b * 512 + q0 + ql)) * 3072 + h * 128 + d]);
  }
  __syncthreads();

  const float scale = 0.051031036307982884f;  // 1/sqrt(128*3)
  for (int pass = 0; pass < 2; ++pass) {
    const int k = tid + pass * 256;
    float4 kvf[32];
    const unsigned short* kp = qkv + ((long)(b * 512 + k)) * 3072 + 1024 + h * 128;
#pragma unroll
    for (int c = 0; c < 16; ++c) {
      uint4 u = ((const uint4*)kp)[c];
      kvf[2 * c + 0] = make_float4(bflo(u.x), bfhi(u.x), bflo(u.y), bfhi(u.y));
      kvf[2 * c + 1] = make_float4(bflo(u.z), bfhi(u.z), bflo(u.w), bfhi(u.w));
    }
    // p2c: row = b*512+k, col = (q0+ql)-k+512 -> contiguous in ql
    const unsigned short* pp = p2c + ((long)(b * 512 + k)) * 1024 + (q0 - k + 512);
    for (int ql = 0; ql < 16; ++ql) {
      float dot = 0.f;
#pragma unroll
      for (int dd = 0; dd < 32; ++dd) {
        float4 qf = ((const float4*)&qs[ql][0])[dd];
        dot += qf.x * kvf[dd].x + qf.y * kvf[dd].y + qf.z * kvf[dd].z + qf.w * kvf[dd].w;
      }
      sc[ql][k] = dot * scale + bf2f(pp[ql]);
    }
  }
  __syncthreads();

  // softmax rows (+ c2p add, contiguous per row: col = q - k + 512)
  const int wave = tid >> 6, lane = tid & 63;
#pragma unroll
  for (int rr = 0; rr < 4; ++rr) {
    const int r = wave * 4 + rr;
    const int q = q0 + r;
    const unsigned short* cp = c2p + ((long)(b * 512 + q)) * 1024 + (q + 512);
    float v[8];
#pragma unroll
    for (int i = 0; i < 8; ++i) {
      int k = lane + 64 * i;
      v[i] = sc[r][k] + bf2f(cp[-k]);
    }
    float m = v[0];
#pragma unroll
    for (int i = 1; i < 8; ++i) m = fmaxf(m, v[i]);
#pragma unroll
    for (int o = 32; o; o >>= 1) m = fmaxf(m, __shfl_xor(m, o));
    float ssum = 0.f;
#pragma unroll
    for (int i = 0; i < 8; ++i) { v[i] = __expf(v[i] - m); ssum += v[i]; }
#pragma unroll
    for (int o = 32; o; o >>= 1) ssum += __shfl_xor(ssum, o);
    const float inv = 1.0f / ssum;
#pragma unroll
    for (int i = 0; i < 8; ++i) sc[r][lane + 64 * i] = v[i] * inv;
  }
  __syncthreads();

  // ctx = probs @ v
  const int d = tid & 127;
  const int qg = tid >> 7;  // 0..1
  float acc[8] = {0, 0, 0, 0, 0, 0, 0, 0};
  const unsigned short* vp = qkv + ((long)(b * 512)) * 3072 + 2048 + h * 128 + d;
  for (int k = 0; k < 512; k += 4) {
    float v0 = bf2f(vp[(long)(k + 0) * 3072]);
    float v1 = bf2f(vp[(long)(k + 1) * 3072]);
    float v2 = bf2f(vp[(long)(k + 2) * 3072]);
    float v3 = bf2f(vp[(long)(k + 3) * 3072]);
#pragma unroll
    for (int qq = 0; qq < 8; ++qq) {
      float4 p = *(const float4*)&sc[qg * 8 + qq][k];
      acc[qq] += p.x * v0 + p.y * v1 + p.z * v2 + p.w * v3;
    }
  }
#pragma unroll
  for (int qq = 0; qq < 8; ++qq) {
    int q = q0 + qg * 8 + qq;
    ctx[((long)(b * 512 + q)) * 1024 + h * 128 + d] = f2bf(acc[qq]);
  }
}

// ---------------------------------------------------------------------------
// Bidirectional LSTM recurrence, data-as-signal sync (no flags, no atomics).
// Grid (32, 2): 32 blocks per direction (all co-resident). Block owns 16
// hidden channels x 4 gates = 64 Whh rows as persistent MFMA A-fragments
// (wave g = gate g). h exchange: per-step 8KB bf16 slot in hx (pre-zeroed),
// producers store with mantissa-LSB forced to 1 (value != 0 sentinel),
// consumers poll the DATA with sc0/sc1 loads (IC-coherent, bypasses the
// non-coherent per-XCD L2s) until every bf16 half is nonzero. One IC round
// trip for detect+load; no atomic contention; producer never waits.
// (Round-3 flag version: 2.34us/step — 32-way atomic RMW on one dword
// serialized at the coherence point + an extra flag round trip.)
// Gate order i,f,g,o (torch). xW is bf16 [B][S][4*512].
// ---------------------------------------------------------------------------
__global__ __launch_bounds__(256) void k_lstm(
    const float* __restrict__ WhhF, const float* __restrict__ WhhR,
    const unsigned short* __restrict__ xWF, const unsigned short* __restrict__ xWR,
    float* __restrict__ out, unsigned short* __restrict__ hx) {
  const int tid = threadIdx.x;
  const int lane = tid & 63;
  const int g = tid >> 6;              // wave index = gate
  const int dir = blockIdx.y;
  const int j0 = blockIdx.x * 16;
  const float* Whh = dir ? WhhR : WhhF;
  const unsigned short* xW = dir ? xWR : xWF;
  unsigned short* hxd = hx + (long)dir * 512 * 4096;  // [s][b][512]

  __shared__ __align__(16) unsigned short hT[16][520];  // [b(+pad)][k] bf16
  __shared__ float gl[4][16][8];                        // [gate][jj][b]
  __shared__ __align__(16) unsigned short hs[8][16];    // staging [b][jj]

  const int m = lane & 15, quad = lane >> 4;
  // preload A fragments: A[m=lane&15][k=quad*8+j] per 32-wide k-tile
  bf8_t afr[16];
  {
    const float* wr = Whh + ((long)(g * 512 + j0 + m)) * 512 + quad * 8;
#pragma unroll
    for (int kt = 0; kt < 16; ++kt) {
      float4 f0 = *(const float4*)(wr + kt * 32);
      float4 f1 = *(const float4*)(wr + kt * 32 + 4);
      bf8_t a;
      a[0] = (__bf16)f0.x; a[1] = (__bf16)f0.y; a[2] = (__bf16)f0.z; a[3] = (__bf16)f0.w;
      a[4] = (__bf16)f1.x; a[5] = (__bf16)f1.y; a[6] = (__bf16)f1.z; a[7] = (__bf16)f1.w;
      afr[kt] = a;
    }
  }
  for (int i = tid; i < 16 * 520; i += 256) (&hT[0][0])[i] = 0;
  float cstate = 0.f;  // valid for tid<128: jj=tid>>3, b=tid&7
  __syncthreads();

  for (int se = 0; se < 512; ++se) {
    const int s = dir ? 511 - se : se;
    // prefetch xW for this step (independent of h_prev; overlaps the poll)
    uint2 uxw = make_uint2(0u, 0u);
    if (m < 8)
      uxw = *(const uint2*)(xW + ((long)(m * 512 + s)) * 2048 + g * 512 + j0 + quad * 4);

    if (se) {
      const int sp = dir ? s + 1 : s - 1;
      // wave g polls its 2 rows (b = 2g, 2g+1); lane window = 8 channels,
      // each window written by exactly one producer's 16B store.
      const unsigned short* hxs = hxd + (long)sp * 4096;
      const unsigned short* p0 = hxs + (2 * g) * 512 + lane * 8;
      const unsigned short* p1 = hxs + (2 * g + 1) * 512 + lane * 8;
      u32x4 r0, r1;
      for (;;) {
        ld2_ic(p0, p1, r0, r1);
        bool ok = true;
#pragma unroll
        for (int t = 0; t < 4; ++t) {
          ok = ok && (r0[t] & 0xffffu) && (r0[t] >> 16) &&
               (r1[t] & 0xffffu) && (r1[t] >> 16);
        }
        if (__ballot(ok) == 0xFFFFFFFFFFFFFFFFull) break;
      }
      *(u32x4*)&hT[2 * g][lane * 8] = r0;
      *(u32x4*)&hT[2 * g + 1][lane * 8] = r1;
      __syncthreads();   // B1: hT complete (prior-step hT/gl reads all done)
    }

    // gates: D[m=jj][n=b] = sum_k Whh[g*512+j0+jj][k] * h_prev[b][k]
    // 4 independent accumulator chains to hide MFMA latency.
    f32x4 a0 = {0.f, 0.f, 0.f, 0.f}, a1 = a0, a2 = a0, a3 = a0;
#pragma unroll
    for (int t = 0; t < 4; ++t) {
      bf8_t b0 = *(const bf8_t*)&hT[m][(4 * t + 0) * 32 + quad * 8];
      bf8_t b1 = *(const bf8_t*)&hT[m][(4 * t + 1) * 32 + quad * 8];
      bf8_t b2 = *(const bf8_t*)&hT[m][(4 * t + 2) * 32 + quad * 8];
      bf8_t b3 = *(const bf8_t*)&hT[m][(4 * t + 3) * 32 + quad * 8];
      a0 = __builtin_amdgcn_mfma_f32_16x16x32_bf16(afr[4 * t + 0], b0, a0, 0, 0, 0);
      a1 = __builtin_amdgcn_mfma_f32_16x16x32_bf16(afr[4 * t + 1], b1, a1, 0, 0, 0);
      a2 = __builtin_amdgcn_mfma_f32_16x16x32_bf16(afr[4 * t + 2], b2, a2, 0, 0, 0);
      a3 = __builtin_amdgcn_mfma_f32_16x16x32_bf16(afr[4 * t + 3], b3, a3, 0, 0, 0);
    }
    if (m < 8) {  // D col = lane&15 = b, rows = quad*4+r = jj
      gl[g][quad * 4 + 0][m] = a0[0] + a1[0] + a2[0] + a3[0] + bflo(uxw.x);
      gl[g][quad * 4 + 1][m] = a0[1] + a1[1] + a2[1] + a3[1] + bfhi(uxw.x);
      gl[g][quad * 4 + 2][m] = a0[2] + a1[2] + a2[2] + a3[2] + bflo(uxw.y);
      gl[g][quad * 4 + 3][m] = a0[3] + a1[3] + a2[3] + a3[3] + bfhi(uxw.y);
    }
    __syncthreads();     // B2: gl ready; all hT reads done
    if (tid < 128) {
      const int jj = tid >> 3, bb = tid & 7;
      float iv = gl[0][jj][bb], fv = gl[1][jj][bb];
      float gv = gl[2][jj][bb], ov = gl[3][jj][bb];
      float is = 1.f / (1.f + __expf(-iv));
      float fs = 1.f / (1.f + __expf(-fv));
      float gt = 2.f / (1.f + __expf(-2.f * gv)) - 1.f;   // tanh
      float os = 1.f / (1.f + __expf(-ov));
      cstate = fs * cstate + is * gt;
      float hv = os * (2.f / (1.f + __expf(-2.f * cstate)) - 1.f);
      hs[bb][jj] = f2bf(hv) | 1;  // LSB-set: nonzero sentinel, <=1 ulp error
      out[((long)(bb * 512 + s)) * 1024 + dir * 512 + j0 + jj] = hv;
    }
    __syncthreads();     // B3: hs ready; all gl reads done
    if (tid < 16) {      // publish 16B chunks; fire-and-forget (no wait!)
      const int b = tid >> 1, half = tid & 1;
      st_ic(hxd + (long)s * 4096 + b * 512 + j0 + half * 8,
            *(const u32x4*)&hs[b][half * 8]);
    }
  }
}

// ---------------------------------------------------------------------------
// Launch. Workspace layout (MB offsets), lifetimes hand-verified:
//   [0,24)  qkv_b (qkv GEMM -> attention) | attn_tmp [0,16) (attn-out -> LN)
//           | xW_f bf16 [0,16) (xW GEMM -> lstm)
//   [16,24) h1_b (attn LN -> inter GEMM) | xW_r bf16 [16,32)
//   [24,40) h0_f (emb LN -> attn LN)     | inter_bf [24,48) (FFN)
//           | hx [32,40) (lstm h exchange; zeroed after inter_bf last read)
//   [40,48) c2p_h (head loop)
//   [48,56) p2c_h (head loop)            | h1_f [48,64) (attn LN -> ffn LN)
//   [64,72) h0_b (emb LN -> qkv GEMM) -> ctx_b (attn -> attn-out GEMM)
//           -> h2_b (ffn LN -> xW GEMMs)
//   [72,78) weight-cast scratch (one weight at a time, stream-serialized)
//   [78,80) relemb_b  [80,82) poskey_b  [82,84) posq_b
//   [84,..) bias_qkv, bsum_f, bsum_r
//   ffn fp32 temp lives in d_out (LSTM later overwrites all of d_out).
// Peak: 85 MB.
// ---------------------------------------------------------------------------
extern "C" void kernel_launch(void* const* d_in, const int* in_sizes, int n_in,
                              void* d_out, int out_size, void* d_ws, size_t ws_size,
                              hipStream_t stream) {
  const float* x         = (const float*)d_in[0];
  const float* pos_emb   = (const float*)d_in[1];
  const float* emb_ln_g  = (const float*)d_in[2];
  const float* emb_ln_b  = (const float*)d_in[3];
  const float* in_proj_w = (const float*)d_in[4];
  const float* q_bias    = (const float*)d_in[5];
  const float* v_bias    = (const float*)d_in[6];
  const float* rel_emb   = (const float*)d_in[7];
  const float* pos_proj_w   = (const float*)d_in[8];
  const float* pos_q_proj_w = (const float*)d_in[9];
  const float* pos_q_proj_b = (const float*)d_in[10];
  const float* attn_out_w = (const float*)d_in[11];
  const float* attn_out_b = (const float*)d_in[12];
  const float* attn_ln_g  = (const float*)d_in[13];
  const float* attn_ln_b  = (const float*)d_in[14];
  const float* inter_w    = (const float*)d_in[15];
  const float* inter_b    = (const float*)d_in[16];
  const float* ffn_out_w  = (const float*)d_in[17];
  const float* ffn_out_b  = (const float*)d_in[18];
  const float* ffn_ln_g   = (const float*)d_in[19];
  const float* ffn_ln_b   = (const float*)d_in[20];
  const float* Wih_f = (const float*)d_in[21];
  const float* Whh_f = (const float*)d_in[22];
  const float* bih_f = (const float*)d_in[23];
  const float* bhh_f = (const float*)d_in[24];
  const float* Wih_r = (const float*)d_in[25];
  const float* Whh_r = (const float*)d_in[26];
  const float* bih_r = (const float*)d_in[27];
  const float* bhh_r = (const float*)d_in[28];
  float* out = (float*)d_out;

  const size_t MB = 1ull << 20;
  const size_t NEED = 85 * MB;
  if (ws_size < NEED) {
    k_sentinel<<<dim3(1), dim3(1), 0, stream>>>(out);
    return;
  }
  char* ws = (char*)d_ws;
  typedef unsigned short u16;
  u16*   qkv_b    = (u16*)(ws + 0);
  float* attn_tmp = (float*)(ws + 0);
  u16*   xW_f     = (u16*)(ws + 0);
  u16*   h1_b     = (u16*)(ws + 16 * MB);
  u16*   xW_r     = (u16*)(ws + 16 * MB);
  float* h0_f     = (float*)(ws + 24 * MB);
  u16*   inter_bf = (u16*)(ws + 24 * MB);
  u16*   hx       = (u16*)(ws + 32 * MB);
  u16*   c2p_h    = (u16*)(ws + 40 * MB);
  u16*   p2c_h    = (u16*)(ws + 48 * MB);
  float* h1_f     = (float*)(ws + 48 * MB);
  u16*   h0_b     = (u16*)(ws + 64 * MB);
  u16*   ctx_b    = (u16*)(ws + 64 * MB);
  u16*   h2_b     = (u16*)(ws + 64 * MB);
  u16*   wscr     = (u16*)(ws + 72 * MB);
  u16*   relemb_b = (u16*)(ws + 78 * MB);
  u16*   poskey_b = (u16*)(ws + 80 * MB);
  u16*   posq_b   = (u16*)(ws + 82 * MB);
  float* bias_qkv = (float*)(ws + 84 * MB);
  float* bsum_f   = (float*)(ws + 84 * MB + 16 * 1024);
  float* bsum_r   = (float*)(ws + 84 * MB + 32 * 1024);
  float* ffn_tmp  = out;  // d_out as fp32 scratch; LSTM overwrites all of it

  const float SCALE = 0.051031036307982884f;  // 1/sqrt(128*3)

  auto cast = [&](const float* src, u16* dst, long n) {
    k_cast_bf16<<<dim3((unsigned)(n / 1024)), dim3(256), 0, stream>>>(src, dst);
  };

  k_build_bias<<<dim3(12), dim3(256), 0, stream>>>(q_bias, v_bias, bias_qkv,
                                                   bih_f, bhh_f, bsum_f,
                                                   bih_r, bhh_r, bsum_r);

  // P1: embeddings LN: h0 = LN(x + pos_emb[s])
  k_layernorm<<<dim3(4096), dim3(256), 0, stream>>>(x, pos_emb, 511u, emb_ln_g,
                                                    emb_ln_b, h0_f, h0_b);

  // P2: qkv = h0 @ in_proj^T + (q_bias,0,v_bias)   [bf16]
  cast(in_proj_w, wscr, 3145728L);
  k_gemm_bt<1><<<dim3(24, 32), dim3(256), 0, stream>>>(
      h0_b, 1024, wscr, 1024, qkv_b, 3072, 1024, bias_qkv, 1.0f);

  // P3: pos_key = rel_emb @ pos_proj^T; pos_q = (rel_emb @ pos_q_proj^T + b)*scale
  cast(rel_emb, relemb_b, 1048576L);
  cast(pos_proj_w, wscr, 1048576L);
  k_gemm_bt<1><<<dim3(8, 8), dim3(256), 0, stream>>>(
      relemb_b, 1024, wscr, 1024, poskey_b, 1024, 1024, (const float*)nullptr, 1.0f);
  cast(pos_q_proj_w, wscr, 1048576L);
  k_gemm_bt<1><<<dim3(8, 8), dim3(256), 0, stream>>>(
      relemb_b, 1024, wscr, 1024, posq_b, 1024, 1024, pos_q_proj_b, SCALE);

  // P4: per-head: c2p_h, p2c_h (Toeplitz bases), attention
  for (int h = 0; h < 8; ++h) {
    k_gemm_bt<1><<<dim3(8, 32), dim3(256), 0, stream>>>(
        qkv_b + h * 128, 3072, poskey_b + h * 128, 1024, c2p_h, 1024, 128,
        (const float*)nullptr, SCALE);
    k_gemm_bt<1><<<dim3(8, 32), dim3(256), 0, stream>>>(
        qkv_b + 1024 + h * 128, 3072, posq_b + h * 128, 1024, p2c_h, 1024, 128,
        (const float*)nullptr, 1.0f);
    k_attention<<<dim3(32, 8), dim3(256), 0, stream>>>(qkv_b, c2p_h, p2c_h, ctx_b, h);
  }

  // P5: attn out projection (fp32) + LN(+h0) -> h1
  cast(attn_out_w, wscr, 1048576L);
  k_gemm_bt<0><<<dim3(8, 32), dim3(256), 0, stream>>>(
      ctx_b, 1024, wscr, 1024, attn_tmp, 1024, 1024, attn_out_b, 1.0f);
  k_layernorm<<<dim3(4096), dim3(256), 0, stream>>>(attn_tmp, h0_f, 0xFFFFFFFFu,
                                                    attn_ln_g, attn_ln_b, h1_f, h1_b);

  // P6: FFN
  cast(inter_w, wscr, 3145728L);
  k_gemm_bt<2><<<dim3(24, 32), dim3(256), 0, stream>>>(
      h1_b, 1024, wscr, 1024, inter_bf, 3072, 1024, inter_b, 1.0f);
  cast(ffn_out_w, wscr, 3145728L);
  k_gemm_bt<0><<<dim3(8, 32), dim3(256), 0, stream>>>(
      inter_bf, 3072, wscr, 3072, ffn_tmp, 1024, 3072, ffn_out_b, 1.0f);
  // hx overlaps inter_bf's tail; zero only after inter_bf's last read (above)
  hipMemsetAsync(hx, 0, 8 * MB, stream);
  k_layernorm<<<dim3(4096), dim3(256), 0, stream>>>(ffn_tmp, h1_f, 0xFFFFFFFFu,
                                                    ffn_ln_g, ffn_ln_b,
                                                    (float*)nullptr, h2_b);

  // P7: LSTM input projections xW = h2 @ Wih^T + (bih+bhh)   [bf16]
  cast(Wih_f, wscr, 2097152L);
  k_gemm_bt<1><<<dim3(16, 32), dim3(256), 0, stream>>>(
      h2_b, 1024, wscr, 1024, xW_f, 2048, 1024, bsum_f, 1.0f);
  cast(Wih_r, wscr, 2097152L);
  k_gemm_bt<1><<<dim3(16, 32), dim3(256), 0, stream>>>(
      h2_b, 1024, wscr, 1024, xW_r, 2048, 1024, bsum_r, 1.0f);

  // P8: bidirectional LSTM recurrence -> writes d_out directly
  k_lstm<<<dim3(32, 2), dim3(256), 0, stream>>>(Whh_f, Whh_r, xW_f, xW_r, out, hx);

  (void)in_sizes; (void)n_in; (void)out_size;
}

// Round 5
// 2142.527 us; speedup vs baseline: 2.5058x; 1.0793x over previous
//
#include <hip/hip_runtime.h>
#include <cstdint>

// ---------------------------------------------------------------------------
// Problem constants: B=8, S=512, H=1024, NH=8, DH=128, INTER=3072, SPAN=512,
// LSTM_H=512. Output fp32 [B,S,H] = concat(hf, hr).
// ---------------------------------------------------------------------------

typedef __bf16 bf8_t __attribute__((ext_vector_type(8)));
typedef float f32x4 __attribute__((ext_vector_type(4)));
typedef unsigned int u32x4 __attribute__((ext_vector_type(4)));

__device__ __forceinline__ unsigned short f2bf(float f) {
  union { float f; unsigned int u; } v; v.f = f;
  unsigned int r = v.u + 0x7fffu + ((v.u >> 16) & 1u);
  return (unsigned short)(r >> 16);
}
__device__ __forceinline__ float bf2f(unsigned short s) {
  union { unsigned int u; float f; } v; v.u = ((unsigned int)s) << 16;
  return v.f;
}
__device__ __forceinline__ float bflo(unsigned int u) {
  union { unsigned int u; float f; } v; v.u = u << 16; return v.f;
}
__device__ __forceinline__ float bfhi(unsigned int u) {
  union { unsigned int u; float f; } v; v.u = u & 0xffff0000u; return v.f;
}

// async global->LDS, 16B per lane; lds dest is wave-uniform base + lane*16
__device__ __forceinline__ void async16(const void* g, void* l) {
  __builtin_amdgcn_global_load_lds(
      (const __attribute__((address_space(1))) void*)g,
      (__attribute__((address_space(3))) void*)l, 16, 0, 0);
}

// --- fine-grained cross-XCD (IC, sc0 sc1) and intra-XCD (L2, sc0) ops ------
__device__ __forceinline__ void ld2_ic(const unsigned short* p0,
                                       const unsigned short* p1,
                                       u32x4& r0, u32x4& r1) {
  asm volatile("global_load_dwordx4 %0, %2, off sc0 sc1\n\t"
               "global_load_dwordx4 %1, %3, off sc0 sc1\n\t"
               "s_waitcnt vmcnt(0)"
               : "=v"(r0), "=v"(r1)
               : "v"(p0), "v"(p1)
               : "memory");
}
__device__ __forceinline__ void ld2_l2(const unsigned short* p0,
                                       const unsigned short* p1,
                                       u32x4& r0, u32x4& r1) {
  asm volatile("global_load_dwordx4 %0, %2, off sc0\n\t"
               "global_load_dwordx4 %1, %3, off sc0\n\t"
               "s_waitcnt vmcnt(0)"
               : "=v"(r0), "=v"(r1)
               : "v"(p0), "v"(p1)
               : "memory");
}
__device__ __forceinline__ void sts_ic(unsigned short* p, unsigned int v) {
  asm volatile("global_store_short %0, %1, off sc0 sc1" :: "v"(p), "v"(v) : "memory");
}
__device__ __forceinline__ void sts_l2(unsigned short* p, unsigned int v) {
  asm volatile("global_store_short %0, %1, off sc0" :: "v"(p), "v"(v) : "memory");
}

// sentinel: ws_size too small -> make absmax unmistakably huge
__global__ void k_sentinel(float* out) { out[0] = 1e30f; }

// ---------------------------------------------------------------------------
// fp32 -> bf16 cast (n divisible by 1024)
// ---------------------------------------------------------------------------
__global__ void k_cast_bf16(const float* __restrict__ in, unsigned short* __restrict__ out) {
  long i = ((long)blockIdx.x * 256 + threadIdx.x) * 4;
  float4 v = *(const float4*)(in + i);
  unsigned int a = (unsigned int)f2bf(v.x) | ((unsigned int)f2bf(v.y) << 16);
  unsigned int b = (unsigned int)f2bf(v.z) | ((unsigned int)f2bf(v.w) << 16);
  *(uint2*)(out + i) = make_uint2(a, b);
}

// build qkv bias [3072] = (q_bias, 0, v_bias) and bsum = bih+bhh per dir
__global__ void k_build_bias(const float* qb, const float* vb, float* qkvBias,
                             const float* bihf, const float* bhhf, float* bsf,
                             const float* bihr, const float* bhhr, float* bsr) {
  int i = blockIdx.x * 256 + threadIdx.x;
  if (i < 3072) {
    float v;
    if (i < 1024) v = qb[i];
    else if (i < 2048) v = 0.f;
    else v = vb[i - 2048];
    qkvBias[i] = v;
  }
  if (i < 2048) {
    bsf[i] = bihf[i] + bhhf[i];
    bsr[i] = bihr[i] + bhhr[i];
  }
}

// ---------------------------------------------------------------------------
// LayerNorm over 1024 cols. in (+res) -> outF (fp32, optional) + outB (bf16,
// optional). res row index = row & resMask (mask=511 for pos_emb broadcast).
// ---------------------------------------------------------------------------
__global__ __launch_bounds__(256) void k_layernorm(
    const float* __restrict__ in, const float* __restrict__ res, unsigned int resMask,
    const float* __restrict__ gamma, const float* __restrict__ beta,
    float* __restrict__ outF, unsigned short* __restrict__ outB) {
  const int row = blockIdx.x;
  const int tid = threadIdx.x;
  float4 v = ((const float4*)(in + (long)row * 1024))[tid];
  if (res) {
    float4 r = ((const float4*)(res + (long)(row & resMask) * 1024))[tid];
    v.x += r.x; v.y += r.y; v.z += r.z; v.w += r.w;
  }
  float s = v.x + v.y + v.z + v.w;
  float q = v.x * v.x + v.y * v.y + v.z * v.z + v.w * v.w;
#pragma unroll
  for (int o = 32; o; o >>= 1) { s += __shfl_down(s, o); q += __shfl_down(q, o); }
  __shared__ float rs[4], rq[4];
  const int wave = tid >> 6, lane = tid & 63;
  if (lane == 0) { rs[wave] = s; rq[wave] = q; }
  __syncthreads();
  s = rs[0] + rs[1] + rs[2] + rs[3];
  q = rq[0] + rq[1] + rq[2] + rq[3];
  const float mean = s * (1.f / 1024.f);
  const float var = q * (1.f / 1024.f) - mean * mean;
  const float rstd = rsqrtf(var + 1e-7f);
  float4 g4 = ((const float4*)gamma)[tid];
  float4 b4 = ((const float4*)beta)[tid];
  float4 o4;
  o4.x = (v.x - mean) * rstd * g4.x + b4.x;
  o4.y = (v.y - mean) * rstd * g4.y + b4.y;
  o4.z = (v.z - mean) * rstd * g4.z + b4.z;
  o4.w = (v.w - mean) * rstd * g4.w + b4.w;
  if (outF) ((float4*)(outF + (long)row * 1024))[tid] = o4;
  if (outB) {
    unsigned int a = (unsigned int)f2bf(o4.x) | ((unsigned int)f2bf(o4.y) << 16);
    unsigned int b = (unsigned int)f2bf(o4.z) | ((unsigned int)f2bf(o4.w) << 16);
    ((uint2*)(outB + (long)row * 1024))[tid] = make_uint2(a, b);
  }
}

// ---------------------------------------------------------------------------
// bf16 MFMA GEMM: C[M,N] = A[M,K] @ B[N,K]^T, 128x128 tile, BK=32,
// global_load_lds staging (m93/m97 structure). Epilogue:
//   v = (acc + bias[col]) * scale;  MODE 0: fp32 store, 1: bf16, 2: gelu->bf16
// All of M,N multiples of 128; K multiple of 32.
// ---------------------------------------------------------------------------
template <int MODE>
__global__ __launch_bounds__(256) void k_gemm_bt(
    const unsigned short* __restrict__ A, int lda,
    const unsigned short* __restrict__ Bm, int ldb,
    void* __restrict__ Cv, int ldc,
    int K, const float* __restrict__ bias, float scale) {
  __shared__ __align__(16) unsigned short As[128 * 32];
  __shared__ __align__(16) unsigned short Bs[128 * 32];
  const int tid = threadIdx.x;
  const int lane = tid & 63;
  const int wave = tid >> 6;
  const int n0 = blockIdx.x * 128;
  const int m0 = blockIdx.y * 128;
  const int srow = tid >> 2;          // 0..63
  const int scol = (tid & 3) * 8;     // 0,8,16,24
  const unsigned short* ag0 = A + (long)(m0 + srow) * lda + scol;
  const unsigned short* ag1 = A + (long)(m0 + 64 + srow) * lda + scol;
  const unsigned short* bg0 = Bm + (long)(n0 + srow) * ldb + scol;
  const unsigned short* bg1 = Bm + (long)(n0 + 64 + srow) * ldb + scol;
  unsigned short* asd0 = &As[(wave * 16) * 32];        // wave-uniform LDS dest
  unsigned short* asd1 = &As[(64 + wave * 16) * 32];
  unsigned short* bsd0 = &Bs[(wave * 16) * 32];
  unsigned short* bsd1 = &Bs[(64 + wave * 16) * 32];
  const int wm = wave >> 1, wn = wave & 1;
  const int mrow = lane & 15;
  const int kq = (lane >> 4) * 8;
  const f32x4 vzero = {0.f, 0.f, 0.f, 0.f};
  f32x4 acc[4][4];
#pragma unroll
  for (int i = 0; i < 4; ++i)
#pragma unroll
    for (int j = 0; j < 4; ++j) acc[i][j] = vzero;

  const int nk = K >> 5;
  for (int kt = 0; kt < nk; ++kt) {
    if (kt) __syncthreads();        // previous tile consumed
    async16(ag0, asd0); async16(ag1, asd1);
    async16(bg0, bsd0); async16(bg1, bsd1);
    ag0 += 32; ag1 += 32; bg0 += 32; bg1 += 32;
    __syncthreads();                // drains vmcnt -> staged data visible
    bf8_t af[4], bf[4];
#pragma unroll
    for (int i = 0; i < 4; ++i)
      af[i] = *(const bf8_t*)&As[(wm * 64 + i * 16 + mrow) * 32 + kq];
#pragma unroll
    for (int j = 0; j < 4; ++j)
      bf[j] = *(const bf8_t*)&Bs[(wn * 64 + j * 16 + mrow) * 32 + kq];
#pragma unroll
    for (int i = 0; i < 4; ++i)
#pragma unroll
      for (int j = 0; j < 4; ++j)
        acc[i][j] = __builtin_amdgcn_mfma_f32_16x16x32_bf16(af[i], bf[j], acc[i][j], 0, 0, 0);
  }
  const int quad = lane >> 4;
  const int cn = lane & 15;
  float* Cf = (float*)Cv;
  unsigned short* Cb = (unsigned short*)Cv;
#pragma unroll
  for (int i = 0; i < 4; ++i) {
#pragma unroll
    for (int j = 0; j < 4; ++j) {
#pragma unroll
      for (int r = 0; r < 4; ++r) {
        int row = m0 + wm * 64 + i * 16 + quad * 4 + r;
        int col = n0 + wn * 64 + j * 16 + cn;
        float v = acc[i][j][r];
        if (bias) v += bias[col];
        v *= scale;
        if (MODE == 2) v = 0.5f * v * (1.0f + erff(v * 0.70710678118654752f));
        long idx = (long)row * ldc + col;
        if (MODE == 0) Cf[idx] = v;
        else Cb[idx] = f2bf(v);
      }
    }
  }
}

// ---------------------------------------------------------------------------
// Attention core, one head per launch. Per (b, 16-row q-tile):
// scores = qk*scale + c2p + p2c; softmax; ctx = probs @ v.
//   c2p_h[b*512+q][rel], p2c_h[b*512+k][rel], rel = q-k+512 (clip is no-op).
// ---------------------------------------------------------------------------
__global__ __launch_bounds__(256) void k_attention(
    const unsigned short* __restrict__ qkv,
    const unsigned short* __restrict__ c2p,
    const unsigned short* __restrict__ p2c,
    unsigned short* __restrict__ ctx, int h) {
  const int tid = threadIdx.x;
  const int qt = blockIdx.x;   // 0..31
  const int b = blockIdx.y;    // 0..7
  const int q0 = qt * 16;
  __shared__ __align__(16) float sc[16][520];
  __shared__ __align__(16) float qs[16][128];

  // load q tile (biased, unscaled)
  for (int i = tid; i < 16 * 128; i += 256) {
    int ql = i >> 7, d = i & 127;
    qs[ql][d] = bf2f(qkv[((long)(b * 512 + q0 + ql)) * 3072 + h * 128 + d]);
  }
  __syncthreads();

  const float scale = 0.051031036307982884f;  // 1/sqrt(128*3)
  for (int pass = 0; pass < 2; ++pass) {
    const int k = tid + pass * 256;
    float4 kvf[32];
    const unsigned short* kp = qkv + ((long)(b * 512 + k)) * 3072 + 1024 + h * 128;
#pragma unroll
    for (int c = 0; c < 16; ++c) {
      uint4 u = ((const uint4*)kp)[c];
      kvf[2 * c + 0] = make_float4(bflo(u.x), bfhi(u.x), bflo(u.y), bfhi(u.y));
      kvf[2 * c + 1] = make_float4(bflo(u.z), bfhi(u.z), bflo(u.w), bfhi(u.w));
    }
    // p2c: row = b*512+k, col = (q0+ql)-k+512 -> contiguous in ql
    const unsigned short* pp = p2c + ((long)(b * 512 + k)) * 1024 + (q0 - k + 512);
    for (int ql = 0; ql < 16; ++ql) {
      float dot = 0.f;
#pragma unroll
      for (int dd = 0; dd < 32; ++dd) {
        float4 qf = ((const float4*)&qs[ql][0])[dd];
        dot += qf.x * kvf[dd].x + qf.y * kvf[dd].y + qf.z * kvf[dd].z + qf.w * kvf[dd].w;
      }
      sc[ql][k] = dot * scale + bf2f(pp[ql]);
    }
  }
  __syncthreads();

  // softmax rows (+ c2p add, contiguous per row: col = q - k + 512)
  const int wave = tid >> 6, lane = tid & 63;
#pragma unroll
  for (int rr = 0; rr < 4; ++rr) {
    const int r = wave * 4 + rr;
    const int q = q0 + r;
    const unsigned short* cp = c2p + ((long)(b * 512 + q)) * 1024 + (q + 512);
    float v[8];
#pragma unroll
    for (int i = 0; i < 8; ++i) {
      int k = lane + 64 * i;
      v[i] = sc[r][k] + bf2f(cp[-k]);
    }
    float m = v[0];
#pragma unroll
    for (int i = 1; i < 8; ++i) m = fmaxf(m, v[i]);
#pragma unroll
    for (int o = 32; o; o >>= 1) m = fmaxf(m, __shfl_xor(m, o));
    float ssum = 0.f;
#pragma unroll
    for (int i = 0; i < 8; ++i) { v[i] = __expf(v[i] - m); ssum += v[i]; }
#pragma unroll
    for (int o = 32; o; o >>= 1) ssum += __shfl_xor(ssum, o);
    const float inv = 1.0f / ssum;
#pragma unroll
    for (int i = 0; i < 8; ++i) sc[r][lane + 64 * i] = v[i] * inv;
  }
  __syncthreads();

  // ctx = probs @ v
  const int d = tid & 127;
  const int qg = tid >> 7;  // 0..1
  float acc[8] = {0, 0, 0, 0, 0, 0, 0, 0};
  const unsigned short* vp = qkv + ((long)(b * 512)) * 3072 + 2048 + h * 128 + d;
  for (int k = 0; k < 512; k += 4) {
    float v0 = bf2f(vp[(long)(k + 0) * 3072]);
    float v1 = bf2f(vp[(long)(k + 1) * 3072]);
    float v2 = bf2f(vp[(long)(k + 2) * 3072]);
    float v3 = bf2f(vp[(long)(k + 3) * 3072]);
#pragma unroll
    for (int qq = 0; qq < 8; ++qq) {
      float4 p = *(const float4*)&sc[qg * 8 + qq][k];
      acc[qq] += p.x * v0 + p.y * v1 + p.z * v2 + p.w * v3;
    }
  }
#pragma unroll
  for (int qq = 0; qq < 8; ++qq) {
    int q = q0 + qg * 8 + qq;
    ctx[((long)(b * 512 + q)) * 1024 + h * 128 + d] = f2bf(acc[qq]);
  }
}

// ---------------------------------------------------------------------------
// Bidirectional LSTM recurrence, data-as-signal + XCD-locality fast path.
// Launch 256 blocks; workers = blocks with (bi&7)<2: dir = bi&7, 16 channels
// at j0 = (bi>>3)*16; others exit. Under the round-robin blockIdx%8->XCD
// heuristic, dir0's 32 blocks land on one XCD, dir1's on another — then the
// h exchange is intra-XCD and the per-XCD L2 (coherent within the XCD) is a
// ~10x faster path than the die-level IC round trip (round-4: 2.1us/step,
// IC-latency-bound). PERFORMANCE hint only, correctness placement-independent:
// producers dual-publish h (plain sc0 store -> mirror/local L2, AND sc0 sc1
// store -> hx/IC authoritative); consumers alternate polling mirror and hx
// with per-bf16-half nonzero validation (values carry mantissa-LSB=1).
// If not co-located the mirror simply never validates and hx always does.
// Both buffers pre-zeroed in-stream. Gate order i,f,g,o; xW bf16 [B][S][2048].
// ---------------------------------------------------------------------------
__global__ __launch_bounds__(256) void k_lstm(
    const float* __restrict__ WhhF, const float* __restrict__ WhhR,
    const unsigned short* __restrict__ xWF, const unsigned short* __restrict__ xWR,
    float* __restrict__ out, unsigned short* __restrict__ hx,
    unsigned short* __restrict__ mir) {
  const int bi = blockIdx.x;
  const int dir = bi & 7;
  if (dir >= 2) return;
  const int j0 = (bi >> 3) * 16;
  const int tid = threadIdx.x;
  const int lane = tid & 63;
  const int g = tid >> 6;              // wave index = gate
  const float* Whh = dir ? WhhR : WhhF;
  const unsigned short* xW = dir ? xWR : xWF;
  unsigned short* hxd = hx + (long)dir * 512 * 4096;   // [s][b][512]
  unsigned short* mird = mir + (long)dir * 512 * 4096;

  __shared__ __align__(16) unsigned short hT[16][520];  // [b(+pad)][k] bf16
  __shared__ float gl[4][8][16];                        // [gate][b][jj]

  const int m = lane & 15, quad = lane >> 4;
  // preload A fragments: A[m=lane&15][k=quad*8+j] per 32-wide k-tile
  bf8_t afr[16];
  {
    const float* wr = Whh + ((long)(g * 512 + j0 + m)) * 512 + quad * 8;
#pragma unroll
    for (int kt = 0; kt < 16; ++kt) {
      float4 f0 = *(const float4*)(wr + kt * 32);
      float4 f1 = *(const float4*)(wr + kt * 32 + 4);
      bf8_t a;
      a[0] = (__bf16)f0.x; a[1] = (__bf16)f0.y; a[2] = (__bf16)f0.z; a[3] = (__bf16)f0.w;
      a[4] = (__bf16)f1.x; a[5] = (__bf16)f1.y; a[6] = (__bf16)f1.z; a[7] = (__bf16)f1.w;
      afr[kt] = a;
    }
  }
  for (int i = tid; i < 16 * 520; i += 256) (&hT[0][0])[i] = 0;
  float cstate = 0.f;  // valid for tid<128: bb=tid>>4, jj=tid&15
  __syncthreads();

  for (int se = 0; se < 512; ++se) {
    const int s = dir ? 511 - se : se;
    // prefetch xW for this step (independent of h_prev; overlaps the poll)
    uint2 uxw = make_uint2(0u, 0u);
    if (m < 8)
      uxw = *(const uint2*)(xW + ((long)(m * 512 + s)) * 2048 + g * 512 + j0 + quad * 4);

    if (se) {
      const int sp = dir ? s + 1 : s - 1;
      // wave g polls its 2 rows (b = 2g, 2g+1), per-bf16-half validation.
      const long so = (long)sp * 4096;
      const int o0 = (2 * g) * 512 + lane * 8;
      const int o1 = (2 * g + 1) * 512 + lane * 8;
      u32x4 r0, r1;
      int tries = 0;
      for (;;) {
        const bool useMir = (tries < 2) || (tries & 1);
        if (useMir) ld2_l2(mird + so + o0, mird + so + o1, r0, r1);
        else        ld2_ic(hxd + so + o0, hxd + so + o1, r0, r1);
        bool ok = true;
#pragma unroll
        for (int t = 0; t < 4; ++t) {
          ok = ok && (r0[t] & 0xffffu) && (r0[t] >> 16) &&
               (r1[t] & 0xffffu) && (r1[t] >> 16);
        }
        if (__ballot(ok) == 0xFFFFFFFFFFFFFFFFull) break;
        ++tries;
        if (!useMir) __builtin_amdgcn_s_sleep(1);
      }
      *(u32x4*)&hT[2 * g][lane * 8] = r0;
      *(u32x4*)&hT[2 * g + 1][lane * 8] = r1;
    }
    __syncthreads();   // B1: hT complete; prior-step gl reads done

    // gates: D[m=jj][n=b] = sum_k Whh[g*512+j0+jj][k] * h_prev[b][k]
    // 4 independent accumulator chains to hide MFMA latency.
    f32x4 a0 = {0.f, 0.f, 0.f, 0.f}, a1 = a0, a2 = a0, a3 = a0;
#pragma unroll
    for (int t = 0; t < 4; ++t) {
      bf8_t b0 = *(const bf8_t*)&hT[m][(4 * t + 0) * 32 + quad * 8];
      bf8_t b1 = *(const bf8_t*)&hT[m][(4 * t + 1) * 32 + quad * 8];
      bf8_t b2 = *(const bf8_t*)&hT[m][(4 * t + 2) * 32 + quad * 8];
      bf8_t b3 = *(const bf8_t*)&hT[m][(4 * t + 3) * 32 + quad * 8];
      a0 = __builtin_amdgcn_mfma_f32_16x16x32_bf16(afr[4 * t + 0], b0, a0, 0, 0, 0);
      a1 = __builtin_amdgcn_mfma_f32_16x16x32_bf16(afr[4 * t + 1], b1, a1, 0, 0, 0);
      a2 = __builtin_amdgcn_mfma_f32_16x16x32_bf16(afr[4 * t + 2], b2, a2, 0, 0, 0);
      a3 = __builtin_amdgcn_mfma_f32_16x16x32_bf16(afr[4 * t + 3], b3, a3, 0, 0, 0);
    }
    if (m < 8) {  // D col = lane&15 = b; rows quad*4+r = jj
      gl[g][m][quad * 4 + 0] = a0[0] + a1[0] + a2[0] + a3[0] + bflo(uxw.x);
      gl[g][m][quad * 4 + 1] = a0[1] + a1[1] + a2[1] + a3[1] + bfhi(uxw.x);
      gl[g][m][quad * 4 + 2] = a0[2] + a1[2] + a2[2] + a3[2] + bflo(uxw.y);
      gl[g][m][quad * 4 + 3] = a0[3] + a1[3] + a2[3] + a3[3] + bfhi(uxw.y);
    }
    __syncthreads();     // B2: gl ready; all hT reads done
    if (tid < 128) {
      const int bb = tid >> 4, jj = tid & 15;
      float iv = gl[0][bb][jj], fv = gl[1][bb][jj];
      float gv = gl[2][bb][jj], ov = gl[3][bb][jj];
      float is = 1.f / (1.f + __expf(-iv));
      float fs = 1.f / (1.f + __expf(-fv));
      float gt = 2.f / (1.f + __expf(-2.f * gv)) - 1.f;   // tanh
      float os = 1.f / (1.f + __expf(-ov));
      cstate = fs * cstate + is * gt;
      float hv = os * (2.f / (1.f + __expf(-2.f * cstate)) - 1.f);
      unsigned int hb = (unsigned int)(f2bf(hv) | 1);  // LSB sentinel, <=1ulp
      const long ho = (long)s * 4096 + bb * 512 + j0 + jj;
      sts_l2(mird + ho, hb);   // fast path (own-XCD L2)
      sts_ic(hxd + ho, hb);    // authoritative (IC, always coherent)
      out[((long)(bb * 512 + s)) * 1024 + dir * 512 + j0 + jj] = hv;
    }
  }
}

// ---------------------------------------------------------------------------
// Launch. Workspace layout (MB offsets), lifetimes hand-verified:
//   [0,24)  qkv_b (qkv GEMM -> attention) | attn_tmp [0,16) (attn-out -> LN)
//           | xW_f bf16 [0,16) (xW GEMM -> lstm)
//   [16,24) h1_b (attn LN -> inter GEMM) | xW_r bf16 [16,32)
//   [24,40) h0_f (emb LN -> attn LN)     | inter_bf [24,48) (FFN)
//           | hx [32,40) (lstm; zeroed after inter_bf last read)
//   [40,48) c2p_h (head loop)            | mir [40,48) (lstm mirror; zeroed
//                                          after inter_bf last read)
//   [48,56) p2c_h (head loop)            | h1_f [48,64) (attn LN -> ffn LN)
//   [64,72) h0_b (emb LN -> qkv GEMM) -> ctx_b (attn -> attn-out GEMM)
//           -> h2_b (ffn LN -> xW GEMMs)
//   [72,78) weight-cast scratch (one weight at a time, stream-serialized)
//   [78,80) relemb_b  [80,82) poskey_b  [82,84) posq_b
//   [84,..) bias_qkv, bsum_f, bsum_r
//   ffn fp32 temp lives in d_out (LSTM later overwrites all of d_out).
// Peak: 85 MB.
// ---------------------------------------------------------------------------
extern "C" void kernel_launch(void* const* d_in, const int* in_sizes, int n_in,
                              void* d_out, int out_size, void* d_ws, size_t ws_size,
                              hipStream_t stream) {
  const float* x         = (const float*)d_in[0];
  const float* pos_emb   = (const float*)d_in[1];
  const float* emb_ln_g  = (const float*)d_in[2];
  const float* emb_ln_b  = (const float*)d_in[3];
  const float* in_proj_w = (const float*)d_in[4];
  const float* q_bias    = (const float*)d_in[5];
  const float* v_bias    = (const float*)d_in[6];
  const float* rel_emb   = (const float*)d_in[7];
  const float* pos_proj_w   = (const float*)d_in[8];
  const float* pos_q_proj_w = (const float*)d_in[9];
  const float* pos_q_proj_b = (const float*)d_in[10];
  const float* attn_out_w = (const float*)d_in[11];
  const float* attn_out_b = (const float*)d_in[12];
  const float* attn_ln_g  = (const float*)d_in[13];
  const float* attn_ln_b  = (const float*)d_in[14];
  const float* inter_w    = (const float*)d_in[15];
  const float* inter_b    = (const float*)d_in[16];
  const float* ffn_out_w  = (const float*)d_in[17];
  const float* ffn_out_b  = (const float*)d_in[18];
  const float* ffn_ln_g   = (const float*)d_in[19];
  const float* ffn_ln_b   = (const float*)d_in[20];
  const float* Wih_f = (const float*)d_in[21];
  const float* Whh_f = (const float*)d_in[22];
  const float* bih_f = (const float*)d_in[23];
  const float* bhh_f = (const float*)d_in[24];
  const float* Wih_r = (const float*)d_in[25];
  const float* Whh_r = (const float*)d_in[26];
  const float* bih_r = (const float*)d_in[27];
  const float* bhh_r = (const float*)d_in[28];
  float* out = (float*)d_out;

  const size_t MB = 1ull << 20;
  const size_t NEED = 85 * MB;
  if (ws_size < NEED) {
    k_sentinel<<<dim3(1), dim3(1), 0, stream>>>(out);
    return;
  }
  char* ws = (char*)d_ws;
  typedef unsigned short u16;
  u16*   qkv_b    = (u16*)(ws + 0);
  float* attn_tmp = (float*)(ws + 0);
  u16*   xW_f     = (u16*)(ws + 0);
  u16*   h1_b     = (u16*)(ws + 16 * MB);
  u16*   xW_r     = (u16*)(ws + 16 * MB);
  float* h0_f     = (float*)(ws + 24 * MB);
  u16*   inter_bf = (u16*)(ws + 24 * MB);
  u16*   hx       = (u16*)(ws + 32 * MB);
  u16*   c2p_h    = (u16*)(ws + 40 * MB);
  u16*   mir      = (u16*)(ws + 40 * MB);
  u16*   p2c_h    = (u16*)(ws + 48 * MB);
  float* h1_f     = (float*)(ws + 48 * MB);
  u16*   h0_b     = (u16*)(ws + 64 * MB);
  u16*   ctx_b    = (u16*)(ws + 64 * MB);
  u16*   h2_b     = (u16*)(ws + 64 * MB);
  u16*   wscr     = (u16*)(ws + 72 * MB);
  u16*   relemb_b = (u16*)(ws + 78 * MB);
  u16*   poskey_b = (u16*)(ws + 80 * MB);
  u16*   posq_b   = (u16*)(ws + 82 * MB);
  float* bias_qkv = (float*)(ws + 84 * MB);
  float* bsum_f   = (float*)(ws + 84 * MB + 16 * 1024);
  float* bsum_r   = (float*)(ws + 84 * MB + 32 * 1024);
  float* ffn_tmp  = out;  // d_out as fp32 scratch; LSTM overwrites all of it

  const float SCALE = 0.051031036307982884f;  // 1/sqrt(128*3)

  auto cast = [&](const float* src, u16* dst, long n) {
    k_cast_bf16<<<dim3((unsigned)(n / 1024)), dim3(256), 0, stream>>>(src, dst);
  };

  k_build_bias<<<dim3(12), dim3(256), 0, stream>>>(q_bias, v_bias, bias_qkv,
                                                   bih_f, bhh_f, bsum_f,
                                                   bih_r, bhh_r, bsum_r);

  // P1: embeddings LN: h0 = LN(x + pos_emb[s])
  k_layernorm<<<dim3(4096), dim3(256), 0, stream>>>(x, pos_emb, 511u, emb_ln_g,
                                                    emb_ln_b, h0_f, h0_b);

  // P2: qkv = h0 @ in_proj^T + (q_bias,0,v_bias)   [bf16]
  cast(in_proj_w, wscr, 3145728L);
  k_gemm_bt<1><<<dim3(24, 32), dim3(256), 0, stream>>>(
      h0_b, 1024, wscr, 1024, qkv_b, 3072, 1024, bias_qkv, 1.0f);

  // P3: pos_key = rel_emb @ pos_proj^T; pos_q = (rel_emb @ pos_q_proj^T + b)*scale
  cast(rel_emb, relemb_b, 1048576L);
  cast(pos_proj_w, wscr, 1048576L);
  k_gemm_bt<1><<<dim3(8, 8), dim3(256), 0, stream>>>(
      relemb_b, 1024, wscr, 1024, poskey_b, 1024, 1024, (const float*)nullptr, 1.0f);
  cast(pos_q_proj_w, wscr, 1048576L);
  k_gemm_bt<1><<<dim3(8, 8), dim3(256), 0, stream>>>(
      relemb_b, 1024, wscr, 1024, posq_b, 1024, 1024, pos_q_proj_b, SCALE);

  // P4: per-head: c2p_h, p2c_h (Toeplitz bases), attention
  for (int h = 0; h < 8; ++h) {
    k_gemm_bt<1><<<dim3(8, 32), dim3(256), 0, stream>>>(
        qkv_b + h * 128, 3072, poskey_b + h * 128, 1024, c2p_h, 1024, 128,
        (const float*)nullptr, SCALE);
    k_gemm_bt<1><<<dim3(8, 32), dim3(256), 0, stream>>>(
        qkv_b + 1024 + h * 128, 3072, posq_b + h * 128, 1024, p2c_h, 1024, 128,
        (const float*)nullptr, 1.0f);
    k_attention<<<dim3(32, 8), dim3(256), 0, stream>>>(qkv_b, c2p_h, p2c_h, ctx_b, h);
  }

  // P5: attn out projection (fp32) + LN(+h0) -> h1
  cast(attn_out_w, wscr, 1048576L);
  k_gemm_bt<0><<<dim3(8, 32), dim3(256), 0, stream>>>(
      ctx_b, 1024, wscr, 1024, attn_tmp, 1024, 1024, attn_out_b, 1.0f);
  k_layernorm<<<dim3(4096), dim3(256), 0, stream>>>(attn_tmp, h0_f, 0xFFFFFFFFu,
                                                    attn_ln_g, attn_ln_b, h1_f, h1_b);

  // P6: FFN
  cast(inter_w, wscr, 3145728L);
  k_gemm_bt<2><<<dim3(24, 32), dim3(256), 0, stream>>>(
      h1_b, 1024, wscr, 1024, inter_bf, 3072, 1024, inter_b, 1.0f);
  cast(ffn_out_w, wscr, 3145728L);
  k_gemm_bt<0><<<dim3(8, 32), dim3(256), 0, stream>>>(
      inter_bf, 3072, wscr, 3072, ffn_tmp, 1024, 3072, ffn_out_b, 1.0f);
  // hx and mir overlap inter_bf; zero only after inter_bf's last read (above)
  hipMemsetAsync(hx, 0, 8 * MB, stream);
  hipMemsetAsync(mir, 0, 8 * MB, stream);
  k_layernorm<<<dim3(4096), dim3(256), 0, stream>>>(ffn_tmp, h1_f, 0xFFFFFFFFu,
                                                    ffn_ln_g, ffn_ln_b,
                                                    (float*)nullptr, h2_b);

  // P7: LSTM input projections xW = h2 @ Wih^T + (bih+bhh)   [bf16]
  cast(Wih_f, wscr, 2097152L);
  k_gemm_bt<1><<<dim3(16, 32), dim3(256), 0, stream>>>(
      h2_b, 1024, wscr, 1024, xW_f, 2048, 1024, bsum_f, 1.0f);
  cast(Wih_r, wscr, 2097152L);
  k_gemm_bt<1><<<dim3(16, 32), dim3(256), 0, stream>>>(
      h2_b, 1024, wscr, 1024, xW_r, 2048, 1024, bsum_r, 1.0f);

  // P8: bidirectional LSTM recurrence -> writes d_out directly.
  // 256 blocks for the %8->XCD co-location heuristic; 192 exit immediately.
  k_lstm<<<dim3(256), dim3(256), 0, stream>>>(Whh_f, Whh_r, xW_f, xW_r, out, hx, mir);

  (void)in_sizes; (void)n_in; (void)out_size;
}